// Round 13
// baseline (962.519 us; speedup 1.0000x reference)
//
#include <hip/hip_runtime.h>
#include <cmath>

#define NUs 32768
#define NIs 8192
#define NNs 40960   // NUs + NIs
#define NEs 2000000
#define CHUNK 2048
#define NB1 977          // ceil(NEs/CHUNK)
#define L1 (256*NB1)     // flat count array length = 250112
#define L4 (L1/4)        // 62528
#define NSA 245          // ceil(L4/256)

typedef unsigned short ushort_t;
typedef unsigned int uint_t;
typedef unsigned long long ull_t;
typedef __attribute__((ext_vector_type(8))) short bf16x8;
typedef __attribute__((ext_vector_type(4))) float f32x4;

__device__ __forceinline__ float4 ld4(const float* p){ return *reinterpret_cast<const float4*>(p); }
__device__ __forceinline__ void st4(float* p, float4 v){ *reinterpret_cast<float4*>(p) = v; }
__device__ __forceinline__ ushort_t f2bf(float f){
    uint_t u = __float_as_uint(f);
    return (ushort_t)((u + 0x7FFFu + ((u >> 16) & 1u)) >> 16);   // RNE
}
__device__ __forceinline__ float bf2f(ushort_t h){ return __uint_as_float((uint_t)h << 16); }

// ================= atomic-free CSR build via two bucket sorts =================

__global__ __launch_bounds__(256) void k_scanA(const int4* __restrict__ in4, int* __restrict__ out,
                                               int* __restrict__ bsums){
    __shared__ int s[256];
    int t = threadIdx.x; int i = blockIdx.x*256 + t;
    int4 v = {0,0,0,0};
    if (i < L4) v = in4[i];
    int sum = v.x+v.y+v.z+v.w;
    s[t] = sum; __syncthreads();
    for (int off=1; off<256; off<<=1){
        int x = (t>=off)? s[t-off] : 0;
        __syncthreads(); s[t] += x; __syncthreads();
    }
    int excl = s[t]-sum;
    if (t == 255) bsums[blockIdx.x] = s[255];
    if (i < L4){
        int o = excl;
        out[4*i]   = o; o += v.x;
        out[4*i+1] = o; o += v.y;
        out[4*i+2] = o; o += v.z;
        out[4*i+3] = o;
    }
}
__global__ void k_scanB(int* __restrict__ b){
    __shared__ int s[256];
    int t = threadIdx.x;
    int v = (t < NSA)? b[t] : 0;
    s[t] = v; __syncthreads();
    for (int off=1; off<256; off<<=1){
        int x = (t>=off)? s[t-off] : 0;
        __syncthreads(); s[t] += x; __syncthreads();
    }
    if (t < NSA) b[t] = s[t]-v;
}
__global__ __launch_bounds__(256) void k_scanC(int4* __restrict__ out, const int* __restrict__ bo){
    int i = blockIdx.x*256 + threadIdx.x;
    if (i >= L4) return;
    int a = bo[blockIdx.x];
    int4 v = out[i]; v.x+=a; v.y+=a; v.z+=a; v.w+=a; out[i] = v;
}

__global__ __launch_bounds__(256) void k_u1cnt(const int* __restrict__ eu, int* __restrict__ C){
    __shared__ int h[256];
    int t = threadIdx.x; h[t] = 0; __syncthreads();
    int base = blockIdx.x*CHUNK;
    #pragma unroll
    for (int k = 0; k < 8; k++){
        int e = base + k*256 + t;
        if (e < NEs) atomicAdd(&h[eu[e]>>7], 1);
    }
    __syncthreads();
    C[t*NB1 + blockIdx.x] = h[t];
}
__global__ __launch_bounds__(256) void k_u1scat(const int* __restrict__ eu, const int* __restrict__ ev,
                                                const int* __restrict__ off, uint_t* __restrict__ stage){
    __shared__ int bo[256]; __shared__ int rk[256];
    int t = threadIdx.x;
    bo[t] = off[t*NB1 + blockIdx.x]; rk[t] = 0;
    __syncthreads();
    int base = blockIdx.x*CHUNK;
    #pragma unroll
    for (int k = 0; k < 8; k++){
        int e = base + k*256 + t;
        if (e < NEs){
            int u = eu[e]; int b = u>>7;
            int r = atomicAdd(&rk[b], 1);
            stage[bo[b]+r] = ((uint_t)u<<13) | (uint_t)(ev[e]-NUs);
        }
    }
}
__global__ __launch_bounds__(256) void k_u2(const uint_t* __restrict__ stage, const int* __restrict__ off,
                                            int* __restrict__ ptr, ushort_t* __restrict__ csr_u,
                                            ull_t* __restrict__ itemin){
    __shared__ int h[128], lb[128], rk[128];
    int b = blockIdx.x, t = threadIdx.x;
    int base = off[b*NB1];
    int end  = (b == 255)? NEs : off[(b+1)*NB1];
    if (t < 128){ h[t] = 0; rk[t] = 0; }
    __syncthreads();
    for (int i = base+t; i < end; i += 256) atomicAdd(&h[(stage[i]>>13)&127], 1);
    __syncthreads();
    if (t < 128) lb[t] = h[t];
    __syncthreads();
    for (int o = 1; o < 128; o <<= 1){
        int x = 0;
        if (t < 128 && t >= o) x = lb[t-o];
        __syncthreads();
        if (t < 128) lb[t] += x;
        __syncthreads();
    }
    if (t < 128){
        int excl = lb[t] - h[t];
        ptr[b*128 + t] = base + excl;
        lb[t] = base + excl;
    }
    __syncthreads();
    for (int i = base+t; i < end; i += 256){
        uint_t p = stage[i];
        int u = (int)(p>>13), item = (int)(p & 0x1FFFu);
        int r = atomicAdd(&rk[u&127], 1);
        int pos = lb[u&127] + r;
        csr_u[pos] = (ushort_t)item;
        itemin[pos] = ((ull_t)item<<36) | ((ull_t)pos<<15) | (ull_t)u;
    }
}
__global__ __launch_bounds__(256) void k_i1cnt(const ull_t* __restrict__ itemin, int* __restrict__ C){
    __shared__ int h[256];
    int t = threadIdx.x; h[t] = 0; __syncthreads();
    int base = blockIdx.x*CHUNK;
    #pragma unroll
    for (int k = 0; k < 8; k++){
        int e = base + k*256 + t;
        if (e < NEs) atomicAdd(&h[(int)((itemin[e]>>41)&255ULL)], 1);
    }
    __syncthreads();
    C[t*NB1 + blockIdx.x] = h[t];
}
__global__ __launch_bounds__(256) void k_i1scat(const ull_t* __restrict__ itemin, const int* __restrict__ off,
                                                ull_t* __restrict__ stage){
    __shared__ int bo[256]; __shared__ int rk[256];
    int t = threadIdx.x;
    bo[t] = off[t*NB1 + blockIdx.x]; rk[t] = 0;
    __syncthreads();
    int base = blockIdx.x*CHUNK;
    #pragma unroll
    for (int k = 0; k < 8; k++){
        int e = base + k*256 + t;
        if (e < NEs){
            ull_t p = itemin[e];
            int b = (int)((p>>41)&255ULL);
            int r = atomicAdd(&rk[b], 1);
            stage[bo[b]+r] = p;
        }
    }
}
__global__ __launch_bounds__(256) void k_i2(const ull_t* __restrict__ stage, const int* __restrict__ off,
                                            int* __restrict__ ptr, ushort_t* __restrict__ csr_iu,
                                            uint_t* __restrict__ csr_ip){
    __shared__ int h[32], lb[32], rk[32];
    int b = blockIdx.x, t = threadIdx.x;
    int base = off[b*NB1];
    int end  = (b == 255)? NEs : off[(b+1)*NB1];
    if (t < 32){ h[t] = 0; rk[t] = 0; }
    __syncthreads();
    for (int i = base+t; i < end; i += 256) atomicAdd(&h[(int)((stage[i]>>36)&31ULL)], 1);
    __syncthreads();
    if (t < 32) lb[t] = h[t];
    __syncthreads();
    for (int o = 1; o < 32; o <<= 1){
        int x = 0;
        if (t < 32 && t >= o) x = lb[t-o];
        __syncthreads();
        if (t < 32) lb[t] += x;
        __syncthreads();
    }
    if (t < 32){
        int excl = lb[t] - h[t];
        ptr[NUs + b*32 + t] = NEs + base + excl;
        lb[t] = base + excl;
    }
    if (b == 255 && t == 0) ptr[NNs] = 2*NEs;
    __syncthreads();
    for (int i = base+t; i < end; i += 256){
        ull_t p = stage[i];
        int key = (int)((p>>36)&31ULL);
        int r = atomicAdd(&rk[key], 1);
        int pos = lb[key] + r;
        csr_iu[pos] = (ushort_t)(p & 32767ULL);
        csr_ip[pos] = (uint_t)((p >> 15) & 0x1FFFFFULL);
    }
}

// ================= MFMA feature GEMM =================
template<int K>
__global__ __launch_bounds__(256) void k_featM(const float* __restrict__ A, const float* __restrict__ W,
                                               const float* __restrict__ bias, float* __restrict__ out){
    int tid = threadIdx.x;
    int wv = tid >> 6, lane = tid & 63;
    int rbase = (blockIdx.x*4 + wv) * 16;
    int c16 = lane & 15;
    int ks8 = (lane >> 4) * 8;
    f32x4 acc0 = {0,0,0,0}, acc1 = {0,0,0,0}, acc2 = {0,0,0,0}, acc3 = {0,0,0,0};
    for (int kt = 0; kt < K; kt += 32){
        const float* ar = A + (size_t)(rbase + c16)*K + kt + ks8;
        bf16x8 ah, al;
        #pragma unroll
        for (int j = 0; j < 8; j++){
            float a = ar[j];
            ushort_t h = f2bf(a); ah[j] = (short)h; al[j] = (short)f2bf(a - bf2f(h));
        }
        #pragma unroll
        for (int ct = 0; ct < 4; ct++){
            const float* wr = W + (size_t)(ct*16 + c16)*K + kt + ks8;
            bf16x8 wh, wl;
            #pragma unroll
            for (int j = 0; j < 8; j++){
                float w = wr[j];
                ushort_t h = f2bf(w); wh[j] = (short)h; wl[j] = (short)f2bf(w - bf2f(h));
            }
            f32x4 acc = (ct==0)? acc0 : (ct==1)? acc1 : (ct==2)? acc2 : acc3;
            acc = __builtin_amdgcn_mfma_f32_16x16x32_bf16(ah, wh, acc, 0, 0, 0);
            acc = __builtin_amdgcn_mfma_f32_16x16x32_bf16(al, wh, acc, 0, 0, 0);
            acc = __builtin_amdgcn_mfma_f32_16x16x32_bf16(ah, wl, acc, 0, 0, 0);
            if (ct==0) acc0 = acc; else if (ct==1) acc1 = acc; else if (ct==2) acc2 = acc; else acc3 = acc;
        }
    }
    #pragma unroll
    for (int ct = 0; ct < 4; ct++){
        f32x4 acc = (ct==0)? acc0 : (ct==1)? acc1 : (ct==2)? acc2 : acc3;
        float bb = bias[ct*16 + c16];
        #pragma unroll
        for (int j = 0; j < 4; j++){
            int row = rbase + (lane >> 4)*4 + j;
            out[(size_t)row*64 + ct*16 + c16] = acc[j] + bb;
        }
    }
}

// ================= KNN SpMM + l2norm =================
__global__ __launch_bounds__(256) void k_spmm_l2(const int* __restrict__ idx, const float* __restrict__ vals,
                                                 const float* __restrict__ src, float* __restrict__ out,
                                                 int stride, int parts){
    int wave = (blockIdx.x*blockDim.x + threadIdx.x) >> 6;
    if (wave >= NIs) return;
    int lane = threadIdx.x & 63;
    const int* cols = idx + stride;
    float acc = 0.f;
    for (int part = 0; part < parts; part++){
        int base = part*81920 + wave*10;
        #pragma unroll
        for (int j = 0; j < 10; j++){
            int e = base + j;
            acc += vals[e] * src[(size_t)cols[e]*64 + lane];
        }
    }
    float ss = acc*acc;
    #pragma unroll
    for (int mset = 1; mset < 64; mset <<= 1) ss += __shfl_xor(ss, mset, 64);
    float nrm = fmaxf(sqrtf(ss), 1e-12f);
    out[(size_t)wave*64 + lane] = acc / nrm;
}

// ================= propagate init: ego/accm + bf16 shadow + row norms =================
__global__ __launch_bounds__(256) void k_init(const float* __restrict__ ue, const float* __restrict__ it,
                                              float* __restrict__ ego, float* __restrict__ accm,
                                              ushort_t* __restrict__ egoB, float* __restrict__ nrm){
    int i = blockIdx.x*blockDim.x + threadIdx.x;
    if (i >= NNs*16) return;
    int n = i >> 4, c = i & 15;
    float4 v = (n < NUs) ? ld4(ue + (size_t)n*64 + c*4)
                         : ld4(it + (size_t)(n-NUs)*64 + c*4);
    st4(ego  + (size_t)n*64 + c*4, v);
    st4(accm + (size_t)n*64 + c*4, v);
    uint2 b;
    b.x = (uint_t)f2bf(v.x) | ((uint_t)f2bf(v.y) << 16);
    b.y = (uint_t)f2bf(v.z) | ((uint_t)f2bf(v.w) << 16);
    *reinterpret_cast<uint2*>(egoB + (size_t)n*64 + c*4) = b;
    float ss = v.x*v.x + v.y*v.y + v.z*v.z + v.w*v.w;
    ss += __shfl_xor(ss, 1, 64);
    ss += __shfl_xor(ss, 2, 64);
    ss += __shfl_xor(ss, 4, 64);
    ss += __shfl_xor(ss, 8, 64);
    if (c == 0) nrm[n] = sqrtf(ss);
}

// ================= mask pass: bf16 neighbor reads + certified f32 fallback =================
__global__ __launch_bounds__(256) void k_mask(const int* __restrict__ ptr, const ushort_t* __restrict__ csr_u,
                                              const float* __restrict__ ego, const ushort_t* __restrict__ egoB,
                                              const float* __restrict__ nrm,
                                              uint_t* __restrict__ mbits, float* __restrict__ dinv){
    int wave = (blockIdx.x*blockDim.x + threadIdx.x) >> 6;
    if (wave >= NUs) return;
    int lane = threadIdx.x & 63;
    int q = lane >> 4, r = lane & 15;
    float4 eu4 = ld4(ego + (size_t)wave*64 + r*4);        // user row: f32 exact
    float nu = nrm[wave] * 0.0078125f;                    // 2^-7 * ||u|| (err bound is 2^-9*||u||*||i||)
    int jb = ptr[wave], je = ptr[wave+1];
    float msum = 0.f; uint_t wacc = 0; int curW = jb >> 5;
    for (int j0 = jb & ~3; j0 < je; j0 += 4){
        int myj = j0 + q;
        bool valid = (myj >= jb) && (myj < je);
        int it = valid ? (int)csr_u[myj] : 0;
        // bf16 neighbor row: 4 elems (8B) per lane -> 128B row, 2 lines
        uint2 bv = *reinterpret_cast<const uint2*>(egoB + (size_t)(NUs+it)*64 + r*4);
        float b0 = __uint_as_float(bv.x << 16);
        float b1 = __uint_as_float(bv.x & 0xFFFF0000u);
        float b2 = __uint_as_float(bv.y << 16);
        float b3 = __uint_as_float(bv.y & 0xFFFF0000u);
        float d = eu4.x*b0 + eu4.y*b1 + eu4.z*b2 + eu4.w*b3;
        d += __shfl_xor(d, 1, 64);
        d += __shfl_xor(d, 2, 64);
        d += __shfl_xor(d, 4, 64);
        d += __shfl_xor(d, 8, 64);
        float thr = nu * nrm[NUs + it];                   // group-uniform
        if (fabsf(d) <= thr){
            // borderline: recompute exact f32 (rare)
            float4 v = ld4(ego + (size_t)(NUs+it)*64 + r*4);
            float dx = eu4.x*v.x + eu4.y*v.y + eu4.z*v.z + eu4.w*v.w;
            dx += __shfl_xor(dx, 1, 64);
            dx += __shfl_xor(dx, 2, 64);
            dx += __shfl_xor(dx, 4, 64);
            dx += __shfl_xor(dx, 8, 64);
            d = dx;
        }
        unsigned long long bal = __ballot(valid && (d >= 0.f));
        uint_t nib = (uint_t)((bal & 1ULL) | ((bal>>15) & 2ULL) | ((bal>>30) & 4ULL) | ((bal>>45) & 8ULL));
        int w = j0 >> 5;
        if (w != curW){
            if (wacc && lane == 0) atomicOr(&mbits[curW], wacc);
            wacc = 0; curW = w;
        }
        wacc |= nib << (j0 & 31);
        msum += (float)__popc(nib);
    }
    if (wacc && lane == 0) atomicOr(&mbits[curW], wacc);
    if (lane == 0) dinv[wave] = rsqrtf(msum + 1.0f);
}

// ================= item-side masked degree =================
__global__ __launch_bounds__(256) void k_itemdeg(const int* __restrict__ ptr, const uint_t* __restrict__ csr_ip,
                                                 const uint_t* __restrict__ mbits, float* __restrict__ dinv){
    int wave = (blockIdx.x*blockDim.x + threadIdx.x) >> 6;
    if (wave >= NIs) return;
    int n = NUs + wave;
    int lane = threadIdx.x & 63;
    int jb = ptr[n], je = ptr[n+1];
    float s = 0.f;
    for (int j = jb + lane; j < je; j += 64){
        uint_t upos = csr_ip[j - NEs];
        s += (float)((mbits[upos >> 5] >> (upos & 31)) & 1u);
    }
    #pragma unroll
    for (int k = 1; k < 64; k <<= 1) s += __shfl_xor(s, k, 64);
    if (lane == 0) dinv[n] = rsqrtf(s + 1.0f);
}

// ================= unmasked dinv =================
__global__ void k_dinvcnt(const int* __restrict__ ptr, float* __restrict__ dinv){
    int n = blockIdx.x*blockDim.x + threadIdx.x;
    if (n < NNs) dinv[n] = rsqrtf((float)(ptr[n+1]-ptr[n]) + 1.0f);
}

// ================= MFMA 64x64 GEMM: gB = bf16((ego@W^T)*dinv[row]) =================
__global__ __launch_bounds__(256) void k_gemmM(const float* __restrict__ ego, const float* __restrict__ W,
                                               const float* __restrict__ dinv, ushort_t* __restrict__ gB){
    int tid = threadIdx.x;
    int wv = tid >> 6, lane = tid & 63;
    int rbase = (blockIdx.x*4 + wv) * 16;
    int c16 = lane & 15;
    int ks = (lane >> 4) * 8;
    const float* ar = ego + (size_t)(rbase + c16)*64;
    bf16x8 ah0, al0, ah1, al1;
    #pragma unroll
    for (int j = 0; j < 8; j++){
        float a = ar[ks + j];
        ushort_t h = f2bf(a); ah0[j] = (short)h; al0[j] = (short)f2bf(a - bf2f(h));
        float b = ar[32 + ks + j];
        ushort_t g = f2bf(b); ah1[j] = (short)g; al1[j] = (short)f2bf(b - bf2f(g));
    }
    float dv[4];
    #pragma unroll
    for (int j = 0; j < 4; j++) dv[j] = dinv[rbase + (lane >> 4)*4 + j];
    #pragma unroll
    for (int ct = 0; ct < 4; ct++){
        const float* wr = W + (size_t)(ct*16 + c16)*64;
        bf16x8 wh0, wl0, wh1, wl1;
        #pragma unroll
        for (int j = 0; j < 8; j++){
            float w = wr[ks + j];
            ushort_t h = f2bf(w); wh0[j] = (short)h; wl0[j] = (short)f2bf(w - bf2f(h));
            float x = wr[32 + ks + j];
            ushort_t g = f2bf(x); wh1[j] = (short)g; wl1[j] = (short)f2bf(x - bf2f(g));
        }
        f32x4 acc = {0.f, 0.f, 0.f, 0.f};
        acc = __builtin_amdgcn_mfma_f32_16x16x32_bf16(ah0, wh0, acc, 0, 0, 0);
        acc = __builtin_amdgcn_mfma_f32_16x16x32_bf16(al0, wh0, acc, 0, 0, 0);
        acc = __builtin_amdgcn_mfma_f32_16x16x32_bf16(ah0, wl0, acc, 0, 0, 0);
        acc = __builtin_amdgcn_mfma_f32_16x16x32_bf16(ah1, wh1, acc, 0, 0, 0);
        acc = __builtin_amdgcn_mfma_f32_16x16x32_bf16(al1, wh1, acc, 0, 0, 0);
        acc = __builtin_amdgcn_mfma_f32_16x16x32_bf16(ah1, wl1, acc, 0, 0, 0);
        #pragma unroll
        for (int j = 0; j < 4; j++){
            int row = rbase + (lane >> 4)*4 + j;
            gB[(size_t)row*64 + ct*16 + c16] = f2bf(acc[j] * dv[j]);
        }
    }
}

// ================= combined aggregation + bf16-shadow/norm epilogue =================
template<bool MASKED>
__global__ __launch_bounds__(256) void k_agg(const int* __restrict__ ptr, const ushort_t* __restrict__ csr_u,
                                             const ushort_t* __restrict__ csr_iu,
                                             const uint_t* __restrict__ csr_ip,
                                             const uint_t* __restrict__ mbits,
                                             const ushort_t* __restrict__ gB, const float* __restrict__ dinv,
                                             const float* __restrict__ bias,
                                             float* __restrict__ egon, float* __restrict__ accm,
                                             ushort_t* __restrict__ egoB, float* __restrict__ nrm){
    int wave = (blockIdx.x*blockDim.x + threadIdx.x) >> 6;
    if (wave >= NNs) return;
    int lane = threadIdx.x & 63;
    int q = lane >> 3, r = lane & 7;     // 8 groups x 8 lanes; each lane covers 8 bf16 cols (16B)
    int jb = ptr[wave], je = ptr[wave+1];
    float acc[8] = {};

    #define ADDROW(row) { \
        uint4 w_ = *reinterpret_cast<const uint4*>(gB + (size_t)(row)*64 + r*8); \
        acc[0] += __uint_as_float(w_.x << 16); acc[1] += __uint_as_float(w_.x & 0xFFFF0000u); \
        acc[2] += __uint_as_float(w_.y << 16); acc[3] += __uint_as_float(w_.y & 0xFFFF0000u); \
        acc[4] += __uint_as_float(w_.z << 16); acc[5] += __uint_as_float(w_.z & 0xFFFF0000u); \
        acc[6] += __uint_as_float(w_.w << 16); acc[7] += __uint_as_float(w_.w & 0xFFFF0000u); }

    if (wave < NUs){
        int j = jb + q;
        for (; j + 8 < je; j += 16){
            int i0 = csr_u[j], i1 = csr_u[j+8];
            bool w0 = true, w1 = true;
            if (MASKED){
                w0 = (mbits[j>>5] >> (j&31)) & 1u;
                w1 = (mbits[(j+8)>>5] >> ((j+8)&31)) & 1u;
            }
            if (w0) ADDROW(NUs + i0);
            if (w1) ADDROW(NUs + i1);
        }
        if (j < je){
            bool w0 = true;
            if (MASKED) w0 = (mbits[j>>5] >> (j&31)) & 1u;
            if (w0) ADDROW(NUs + (int)csr_u[j]);
        }
    } else {
        const ushort_t* ciu = csr_iu - NEs;
        const uint_t*   cip = csr_ip - NEs;
        int j = jb + q;
        for (; j + 8 < je; j += 16){
            int u0 = ciu[j], u1 = ciu[j+8];
            bool w0 = true, w1 = true;
            if (MASKED){
                uint_t a0 = cip[j], a1 = cip[j+8];
                w0 = (mbits[a0>>5] >> (a0&31)) & 1u;
                w1 = (mbits[a1>>5] >> (a1&31)) & 1u;
            }
            if (w0) ADDROW(u0);
            if (w1) ADDROW(u1);
        }
        if (j < je){
            int u0 = ciu[j];
            bool w0 = true;
            if (MASKED){
                uint_t a0 = cip[j];
                w0 = (mbits[a0>>5] >> (a0&31)) & 1u;
            }
            if (w0) ADDROW(u0);
        }
    }
    #undef ADDROW

    #pragma unroll
    for (int k = 0; k < 8; k++){
        acc[k] += __shfl_xor(acc[k], 8, 64);
        acc[k] += __shfl_xor(acc[k], 16, 64);
        acc[k] += __shfl_xor(acc[k], 32, 64);
    }
    if (q == 0){
        float dn = dinv[wave];
        uint4 w_ = *reinterpret_cast<const uint4*>(gB + (size_t)wave*64 + r*8);
        float gs[8];
        gs[0] = __uint_as_float(w_.x << 16); gs[1] = __uint_as_float(w_.x & 0xFFFF0000u);
        gs[2] = __uint_as_float(w_.y << 16); gs[3] = __uint_as_float(w_.y & 0xFFFF0000u);
        gs[4] = __uint_as_float(w_.z << 16); gs[5] = __uint_as_float(w_.z & 0xFFFF0000u);
        gs[6] = __uint_as_float(w_.w << 16); gs[7] = __uint_as_float(w_.w & 0xFFFF0000u);
        float o[8];
        #pragma unroll
        for (int k = 0; k < 8; k++) o[k] = dn*(acc[k] + gs[k]) + bias[r*8 + k];
        float* eg = egon + (size_t)wave*64 + r*8;
        float* am = accm + (size_t)wave*64 + r*8;
        float4 o0 = {o[0],o[1],o[2],o[3]}, o1 = {o[4],o[5],o[6],o[7]};
        st4(eg, o0); st4(eg+4, o1);
        float4 a0 = ld4(am), a1 = ld4(am+4);
        a0.x+=o[0]; a0.y+=o[1]; a0.z+=o[2]; a0.w+=o[3];
        a1.x+=o[4]; a1.y+=o[5]; a1.z+=o[6]; a1.w+=o[7];
        st4(am, a0); st4(am+4, a1);
        // bf16 shadow + row norm for next layer's mask
        uint4 eb;
        eb.x = (uint_t)f2bf(o[0]) | ((uint_t)f2bf(o[1]) << 16);
        eb.y = (uint_t)f2bf(o[2]) | ((uint_t)f2bf(o[3]) << 16);
        eb.z = (uint_t)f2bf(o[4]) | ((uint_t)f2bf(o[5]) << 16);
        eb.w = (uint_t)f2bf(o[6]) | ((uint_t)f2bf(o[7]) << 16);
        *reinterpret_cast<uint4*>(egoB + (size_t)wave*64 + r*8) = eb;
        float ss = 0.f;
        #pragma unroll
        for (int k = 0; k < 8; k++) ss += o[k]*o[k];
        ss += __shfl_xor(ss, 1, 64);
        ss += __shfl_xor(ss, 2, 64);
        ss += __shfl_xor(ss, 4, 64);
        if (r == 0) nrm[wave] = sqrtf(ss);
    }
}

// ================= final =================
__global__ __launch_bounds__(256) void k_final(const float* __restrict__ accm, const float* __restrict__ extra,
                                               float* __restrict__ out, int p){
    int i = blockIdx.x*blockDim.x + threadIdx.x;
    if (i >= NNs*16) return;
    int n = i >> 4, c = i & 15;
    float4 v = ld4(accm + (size_t)n*64 + c*4);
    const float third = 1.0f/3.0f;
    v.x *= third; v.y *= third; v.z *= third; v.w *= third;
    if (n >= NUs){
        float4 e = ld4(extra + (size_t)(n-NUs)*64 + c*4);
        v.x += e.x; v.y += e.y; v.z += e.z; v.w += e.w;
    }
    st4(out + (size_t)n*192 + p*64 + c*4, v);
}

extern "C" void kernel_launch(void* const* d_in, const int* in_sizes, int n_in,
                              void* d_out, int out_size, void* d_ws, size_t ws_size,
                              hipStream_t stream){
    const float* user_emb = (const float*)d_in[0];
    const float* item_emb = (const float*)d_in[1];
    const float* v_feat   = (const float*)d_in[2];
    const float* t_feat   = (const float*)d_in[3];
    const float* Wi       = (const float*)d_in[4];
    const float* bi       = (const float*)d_in[5];
    const float* Wt       = (const float*)d_in[6];
    const float* bt       = (const float*)d_in[7];
    const float* convW    = (const float*)d_in[8];
    const float* convb    = (const float*)d_in[9];
    const int*   edge     = (const int*)d_in[10];
    const int*   img_idx  = (const int*)d_in[11];
    const float* img_vals = (const float*)d_in[12];
    const int*   txt_idx  = (const int*)d_in[13];
    const float* txt_vals = (const float*)d_in[14];
    const int*   mm_idx   = (const int*)d_in[15];
    const float* mm_vals  = (const float*)d_in[16];
    float* out = (float*)d_out;

    const int* eu = edge;
    const int* ev = edge + NEs;

    char* wsb = (char*)d_ws;
    size_t off = 0;
    auto alloc = [&](size_t b)->char*{ char* p = wsb + off; off = (off + b + 255) & ~(size_t)255; return p; };
    int*      ptr    = (int*)     alloc((size_t)(NNs+1)*4);
    int*      Cflat  = (int*)     alloc((size_t)L1*4);
    int*      bsums  = (int*)     alloc(256*4);
    uint_t*   stageu = (uint_t*)  alloc((size_t)NEs*4);
    ull_t*    itemin = (ull_t*)   alloc((size_t)NEs*8);
    ull_t*    stagei = (ull_t*)   alloc((size_t)NEs*8);
    ushort_t* csr_u  = (ushort_t*)alloc((size_t)NEs*2);
    ushort_t* csr_iu = (ushort_t*)alloc((size_t)NEs*2);
    uint_t*   csr_ip = (uint_t*)  alloc((size_t)NEs*4);
    uint_t*   mbits  = (uint_t*)  alloc((size_t)((NEs+63)/64)*8);
    float*    dinv   = (float*)   alloc((size_t)NNs*4);
    float*    nrm    = (float*)   alloc((size_t)NNs*4);
    float*    ego_a  = (float*)   alloc((size_t)NNs*64*4);
    float*    ego_b  = (float*)   alloc((size_t)NNs*64*4);
    ushort_t* egoB   = (ushort_t*)alloc((size_t)NNs*64*2);
    ushort_t* gB     = (ushort_t*)alloc((size_t)NNs*64*2);
    float*    accm   = (float*)   alloc((size_t)NNs*64*4);
    float*    vemb   = (float*)   alloc((size_t)NIs*64*4);
    float*    temb   = (float*)   alloc((size_t)NIs*64*4);
    float*    hbuf   = (float*)   alloc((size_t)NIs*64*4);
    float*    h1buf  = (float*)   alloc((size_t)NIs*64*4);
    float*    h2buf  = (float*)   alloc((size_t)NIs*64*4);

    // ---- CSR build: user bucket sort ----
    k_u1cnt<<<NB1, 256, 0, stream>>>(eu, Cflat);
    k_scanA<<<NSA, 256, 0, stream>>>((const int4*)Cflat, Cflat, bsums);
    k_scanB<<<1, 256, 0, stream>>>(bsums);
    k_scanC<<<NSA, 256, 0, stream>>>((int4*)Cflat, bsums);
    k_u1scat<<<NB1, 256, 0, stream>>>(eu, ev, Cflat, stageu);
    k_u2<<<256, 256, 0, stream>>>(stageu, Cflat, ptr, csr_u, itemin);
    // ---- CSR build: item bucket sort (carries upos) ----
    k_i1cnt<<<NB1, 256, 0, stream>>>(itemin, Cflat);
    k_scanA<<<NSA, 256, 0, stream>>>((const int4*)Cflat, Cflat, bsums);
    k_scanB<<<1, 256, 0, stream>>>(bsums);
    k_scanC<<<NSA, 256, 0, stream>>>((int4*)Cflat, bsums);
    k_i1scat<<<NB1, 256, 0, stream>>>(itemin, Cflat, stagei);
    k_i2<<<256, 256, 0, stream>>>(stagei, Cflat, ptr, csr_iu, csr_ip);

    // ---- feature embeddings (MFMA) ----
    k_featM<1024><<<128, 256, 0, stream>>>(v_feat, Wi, bi, vemb);
    k_featM<384> <<<128, 256, 0, stream>>>(t_feat, Wt, bt, temb);

    // ---- KNN spmm + l2norm ----
    k_spmm_l2<<<2048, 256, 0, stream>>>(mm_idx,  mm_vals,  item_emb, hbuf,  163840, 2);
    k_spmm_l2<<<2048, 256, 0, stream>>>(img_idx, img_vals, vemb,     h1buf, 81920, 1);
    k_spmm_l2<<<2048, 256, 0, stream>>>(txt_idx, txt_vals, temb,     h2buf, 81920, 1);

    // ---- propagates ----
    auto propagate = [&](const float* item_part, bool filtered, const float* extra, int pcol){
        k_init<<<2560, 256, 0, stream>>>(user_emb, item_part, ego_a, accm, egoB, nrm);
        float* cur = ego_a; float* nxt = ego_b;
        if (!filtered) k_dinvcnt<<<160, 256, 0, stream>>>(ptr, dinv);
        for (int l = 0; l < 2; l++){
            if (filtered){
                hipMemsetAsync(mbits, 0, (size_t)((NEs+63)/64)*8, stream);
                k_mask<<<8192, 256, 0, stream>>>(ptr, csr_u, cur, egoB, nrm, mbits, dinv);
                k_itemdeg<<<2048, 256, 0, stream>>>(ptr, csr_ip, mbits, dinv);
            }
            k_gemmM<<<640, 256, 0, stream>>>(cur, convW + l*64*64, dinv, gB);
            if (filtered)
                k_agg<true><<<10240, 256, 0, stream>>>(ptr, csr_u, csr_iu, csr_ip, mbits, gB, dinv, convb + l*64, nxt, accm, egoB, nrm);
            else
                k_agg<false><<<10240, 256, 0, stream>>>(ptr, csr_u, csr_iu, nullptr, nullptr, gB, dinv, convb + l*64, nxt, accm, egoB, nrm);
            float* t = cur; cur = nxt; nxt = t;
        }
        k_final<<<2560, 256, 0, stream>>>(accm, extra, out, pcol);
    };

    propagate(vemb,     true,  h1buf, 1);   // u_v / i_v
    propagate(temb,     true,  h2buf, 2);   // u_t / i_t
    propagate(item_emb, false, hbuf,  0);   // u_g / i_g
}

// Round 14
// 874.463 us; speedup vs baseline: 1.1007x; 1.1007x over previous
//
#include <hip/hip_runtime.h>
#include <cmath>

#define NUs 32768
#define NIs 8192
#define NNs 40960   // NUs + NIs
#define NEs 2000000
#define CHUNK 2048
#define NB1 977          // ceil(NEs/CHUNK)
#define L1 (256*NB1)     // flat count array length = 250112
#define L4 (L1/4)        // 62528
#define NSA 245          // ceil(L4/256)

typedef unsigned short ushort_t;
typedef unsigned int uint_t;
typedef unsigned long long ull_t;
typedef __attribute__((ext_vector_type(8))) short bf16x8;
typedef __attribute__((ext_vector_type(4))) float f32x4;

__device__ __forceinline__ float4 ld4(const float* p){ return *reinterpret_cast<const float4*>(p); }
__device__ __forceinline__ void st4(float* p, float4 v){ *reinterpret_cast<float4*>(p) = v; }
__device__ __forceinline__ ushort_t f2bf(float f){
    uint_t u = __float_as_uint(f);
    return (ushort_t)((u + 0x7FFFu + ((u >> 16) & 1u)) >> 16);   // RNE
}
__device__ __forceinline__ float bf2f(ushort_t h){ return __uint_as_float((uint_t)h << 16); }

// ================= atomic-free CSR build via two bucket sorts =================

__global__ __launch_bounds__(256) void k_scanA(const int4* __restrict__ in4, int* __restrict__ out,
                                               int* __restrict__ bsums){
    __shared__ int s[256];
    int t = threadIdx.x; int i = blockIdx.x*256 + t;
    int4 v = {0,0,0,0};
    if (i < L4) v = in4[i];
    int sum = v.x+v.y+v.z+v.w;
    s[t] = sum; __syncthreads();
    for (int off=1; off<256; off<<=1){
        int x = (t>=off)? s[t-off] : 0;
        __syncthreads(); s[t] += x; __syncthreads();
    }
    int excl = s[t]-sum;
    if (t == 255) bsums[blockIdx.x] = s[255];
    if (i < L4){
        int o = excl;
        out[4*i]   = o; o += v.x;
        out[4*i+1] = o; o += v.y;
        out[4*i+2] = o; o += v.z;
        out[4*i+3] = o;
    }
}
__global__ void k_scanB(int* __restrict__ b){
    __shared__ int s[256];
    int t = threadIdx.x;
    int v = (t < NSA)? b[t] : 0;
    s[t] = v; __syncthreads();
    for (int off=1; off<256; off<<=1){
        int x = (t>=off)? s[t-off] : 0;
        __syncthreads(); s[t] += x; __syncthreads();
    }
    if (t < NSA) b[t] = s[t]-v;
}
__global__ __launch_bounds__(256) void k_scanC(int4* __restrict__ out, const int* __restrict__ bo){
    int i = blockIdx.x*256 + threadIdx.x;
    if (i >= L4) return;
    int a = bo[blockIdx.x];
    int4 v = out[i]; v.x+=a; v.y+=a; v.z+=a; v.w+=a; out[i] = v;
}

__global__ __launch_bounds__(256) void k_u1cnt(const int* __restrict__ eu, int* __restrict__ C){
    __shared__ int h[256];
    int t = threadIdx.x; h[t] = 0; __syncthreads();
    int base = blockIdx.x*CHUNK;
    #pragma unroll
    for (int k = 0; k < 8; k++){
        int e = base + k*256 + t;
        if (e < NEs) atomicAdd(&h[eu[e]>>7], 1);
    }
    __syncthreads();
    C[t*NB1 + blockIdx.x] = h[t];
}
__global__ __launch_bounds__(256) void k_u1scat(const int* __restrict__ eu, const int* __restrict__ ev,
                                                const int* __restrict__ off, uint_t* __restrict__ stage){
    __shared__ int bo[256]; __shared__ int rk[256];
    int t = threadIdx.x;
    bo[t] = off[t*NB1 + blockIdx.x]; rk[t] = 0;
    __syncthreads();
    int base = blockIdx.x*CHUNK;
    #pragma unroll
    for (int k = 0; k < 8; k++){
        int e = base + k*256 + t;
        if (e < NEs){
            int u = eu[e]; int b = u>>7;
            int r = atomicAdd(&rk[b], 1);
            stage[bo[b]+r] = ((uint_t)u<<13) | (uint_t)(ev[e]-NUs);
        }
    }
}
__global__ __launch_bounds__(256) void k_u2(const uint_t* __restrict__ stage, const int* __restrict__ off,
                                            int* __restrict__ ptr, ushort_t* __restrict__ csr_u,
                                            ull_t* __restrict__ itemin){
    __shared__ int h[128], lb[128], rk[128];
    int b = blockIdx.x, t = threadIdx.x;
    int base = off[b*NB1];
    int end  = (b == 255)? NEs : off[(b+1)*NB1];
    if (t < 128){ h[t] = 0; rk[t] = 0; }
    __syncthreads();
    for (int i = base+t; i < end; i += 256) atomicAdd(&h[(stage[i]>>13)&127], 1);
    __syncthreads();
    if (t < 128) lb[t] = h[t];
    __syncthreads();
    for (int o = 1; o < 128; o <<= 1){
        int x = 0;
        if (t < 128 && t >= o) x = lb[t-o];
        __syncthreads();
        if (t < 128) lb[t] += x;
        __syncthreads();
    }
    if (t < 128){
        int excl = lb[t] - h[t];
        ptr[b*128 + t] = base + excl;
        lb[t] = base + excl;
    }
    __syncthreads();
    for (int i = base+t; i < end; i += 256){
        uint_t p = stage[i];
        int u = (int)(p>>13), item = (int)(p & 0x1FFFu);
        int r = atomicAdd(&rk[u&127], 1);
        int pos = lb[u&127] + r;
        csr_u[pos] = (ushort_t)item;
        itemin[pos] = ((ull_t)item<<36) | ((ull_t)pos<<15) | (ull_t)u;
    }
}
__global__ __launch_bounds__(256) void k_i1cnt(const ull_t* __restrict__ itemin, int* __restrict__ C){
    __shared__ int h[256];
    int t = threadIdx.x; h[t] = 0; __syncthreads();
    int base = blockIdx.x*CHUNK;
    #pragma unroll
    for (int k = 0; k < 8; k++){
        int e = base + k*256 + t;
        if (e < NEs) atomicAdd(&h[(int)((itemin[e]>>41)&255ULL)], 1);
    }
    __syncthreads();
    C[t*NB1 + blockIdx.x] = h[t];
}
__global__ __launch_bounds__(256) void k_i1scat(const ull_t* __restrict__ itemin, const int* __restrict__ off,
                                                ull_t* __restrict__ stage){
    __shared__ int bo[256]; __shared__ int rk[256];
    int t = threadIdx.x;
    bo[t] = off[t*NB1 + blockIdx.x]; rk[t] = 0;
    __syncthreads();
    int base = blockIdx.x*CHUNK;
    #pragma unroll
    for (int k = 0; k < 8; k++){
        int e = base + k*256 + t;
        if (e < NEs){
            ull_t p = itemin[e];
            int b = (int)((p>>41)&255ULL);
            int r = atomicAdd(&rk[b], 1);
            stage[bo[b]+r] = p;
        }
    }
}
__global__ __launch_bounds__(256) void k_i2(const ull_t* __restrict__ stage, const int* __restrict__ off,
                                            int* __restrict__ ptr, ushort_t* __restrict__ csr_iu,
                                            uint_t* __restrict__ csr_ip){
    __shared__ int h[32], lb[32], rk[32];
    int b = blockIdx.x, t = threadIdx.x;
    int base = off[b*NB1];
    int end  = (b == 255)? NEs : off[(b+1)*NB1];
    if (t < 32){ h[t] = 0; rk[t] = 0; }
    __syncthreads();
    for (int i = base+t; i < end; i += 256) atomicAdd(&h[(int)((stage[i]>>36)&31ULL)], 1);
    __syncthreads();
    if (t < 32) lb[t] = h[t];
    __syncthreads();
    for (int o = 1; o < 32; o <<= 1){
        int x = 0;
        if (t < 32 && t >= o) x = lb[t-o];
        __syncthreads();
        if (t < 32) lb[t] += x;
        __syncthreads();
    }
    if (t < 32){
        int excl = lb[t] - h[t];
        ptr[NUs + b*32 + t] = NEs + base + excl;
        lb[t] = base + excl;
    }
    if (b == 255 && t == 0) ptr[NNs] = 2*NEs;
    __syncthreads();
    for (int i = base+t; i < end; i += 256){
        ull_t p = stage[i];
        int key = (int)((p>>36)&31ULL);
        int r = atomicAdd(&rk[key], 1);
        int pos = lb[key] + r;
        csr_iu[pos] = (ushort_t)(p & 32767ULL);
        csr_ip[pos] = (uint_t)((p >> 15) & 0x1FFFFFULL);
    }
}

// ================= MFMA feature GEMM =================
template<int K>
__global__ __launch_bounds__(256) void k_featM(const float* __restrict__ A, const float* __restrict__ W,
                                               const float* __restrict__ bias, float* __restrict__ out){
    int tid = threadIdx.x;
    int wv = tid >> 6, lane = tid & 63;
    int rbase = (blockIdx.x*4 + wv) * 16;
    int c16 = lane & 15;
    int ks8 = (lane >> 4) * 8;
    f32x4 acc0 = {0,0,0,0}, acc1 = {0,0,0,0}, acc2 = {0,0,0,0}, acc3 = {0,0,0,0};
    for (int kt = 0; kt < K; kt += 32){
        const float* ar = A + (size_t)(rbase + c16)*K + kt + ks8;
        bf16x8 ah, al;
        #pragma unroll
        for (int j = 0; j < 8; j++){
            float a = ar[j];
            ushort_t h = f2bf(a); ah[j] = (short)h; al[j] = (short)f2bf(a - bf2f(h));
        }
        #pragma unroll
        for (int ct = 0; ct < 4; ct++){
            const float* wr = W + (size_t)(ct*16 + c16)*K + kt + ks8;
            bf16x8 wh, wl;
            #pragma unroll
            for (int j = 0; j < 8; j++){
                float w = wr[j];
                ushort_t h = f2bf(w); wh[j] = (short)h; wl[j] = (short)f2bf(w - bf2f(h));
            }
            f32x4 acc = (ct==0)? acc0 : (ct==1)? acc1 : (ct==2)? acc2 : acc3;
            acc = __builtin_amdgcn_mfma_f32_16x16x32_bf16(ah, wh, acc, 0, 0, 0);
            acc = __builtin_amdgcn_mfma_f32_16x16x32_bf16(al, wh, acc, 0, 0, 0);
            acc = __builtin_amdgcn_mfma_f32_16x16x32_bf16(ah, wl, acc, 0, 0, 0);
            if (ct==0) acc0 = acc; else if (ct==1) acc1 = acc; else if (ct==2) acc2 = acc; else acc3 = acc;
        }
    }
    #pragma unroll
    for (int ct = 0; ct < 4; ct++){
        f32x4 acc = (ct==0)? acc0 : (ct==1)? acc1 : (ct==2)? acc2 : acc3;
        float bb = bias[ct*16 + c16];
        #pragma unroll
        for (int j = 0; j < 4; j++){
            int row = rbase + (lane >> 4)*4 + j;
            out[(size_t)row*64 + ct*16 + c16] = acc[j] + bb;
        }
    }
}

// ================= KNN SpMM + l2norm =================
__global__ __launch_bounds__(256) void k_spmm_l2(const int* __restrict__ idx, const float* __restrict__ vals,
                                                 const float* __restrict__ src, float* __restrict__ out,
                                                 int stride, int parts){
    int wave = (blockIdx.x*blockDim.x + threadIdx.x) >> 6;
    if (wave >= NIs) return;
    int lane = threadIdx.x & 63;
    const int* cols = idx + stride;
    float acc = 0.f;
    for (int part = 0; part < parts; part++){
        int base = part*81920 + wave*10;
        #pragma unroll
        for (int j = 0; j < 10; j++){
            int e = base + j;
            acc += vals[e] * src[(size_t)cols[e]*64 + lane];
        }
    }
    float ss = acc*acc;
    #pragma unroll
    for (int mset = 1; mset < 64; mset <<= 1) ss += __shfl_xor(ss, mset, 64);
    float nrm = fmaxf(sqrtf(ss), 1e-12f);
    out[(size_t)wave*64 + lane] = acc / nrm;
}

// ================= propagate init =================
__global__ __launch_bounds__(256) void k_init(const float* __restrict__ ue, const float* __restrict__ it,
                                              float* __restrict__ ego, float* __restrict__ accm){
    int i = blockIdx.x*blockDim.x + threadIdx.x;
    if (i >= NNs*16) return;
    int n = i >> 4, c = i & 15;
    float4 v = (n < NUs) ? ld4(ue + (size_t)n*64 + c*4)
                         : ld4(it + (size_t)(n-NUs)*64 + c*4);
    st4(ego  + (size_t)n*64 + c*4, v);
    st4(accm + (size_t)n*64 + c*4, v);
}

// ================= mask pass: word-aggregated, 2-way unrolled (8 edges/iter) =================
__global__ __launch_bounds__(256) void k_mask(const int* __restrict__ ptr, const ushort_t* __restrict__ csr_u,
                                              const float* __restrict__ ego,
                                              uint_t* __restrict__ mbits, float* __restrict__ dinv){
    int wave = (blockIdx.x*blockDim.x + threadIdx.x) >> 6;
    if (wave >= NUs) return;
    int lane = threadIdx.x & 63;
    int q = lane >> 4, r = lane & 15;
    float4 eu4 = ld4(ego + (size_t)wave*64 + r*4);
    int jb = ptr[wave], je = ptr[wave+1];
    float msum = 0.f; uint_t wacc = 0; int curW = jb >> 5;
    for (int j0 = jb & ~7; j0 < je; j0 += 8){
        int jA = j0 + q, jB = j0 + 4 + q;
        bool vA = (jA >= jb) && (jA < je);
        bool vB = (jB >= jb) && (jB < je);
        int iA = vA ? (int)csr_u[jA] : 0;
        int iB = vB ? (int)csr_u[jB] : 0;
        float4 a = ld4(ego + (size_t)(NUs+iA)*64 + r*4);
        float4 b = ld4(ego + (size_t)(NUs+iB)*64 + r*4);
        float d0 = eu4.x*a.x + eu4.y*a.y + eu4.z*a.z + eu4.w*a.w;
        float d1 = eu4.x*b.x + eu4.y*b.y + eu4.z*b.z + eu4.w*b.w;
        d0 += __shfl_xor(d0, 1, 64); d1 += __shfl_xor(d1, 1, 64);
        d0 += __shfl_xor(d0, 2, 64); d1 += __shfl_xor(d1, 2, 64);
        d0 += __shfl_xor(d0, 4, 64); d1 += __shfl_xor(d1, 4, 64);
        d0 += __shfl_xor(d0, 8, 64); d1 += __shfl_xor(d1, 8, 64);
        ull_t balA = __ballot(vA && (d0 >= 0.f));
        ull_t balB = __ballot(vB && (d1 >= 0.f));
        uint_t nibA = (uint_t)((balA & 1ULL) | ((balA>>15) & 2ULL) | ((balA>>30) & 4ULL) | ((balA>>45) & 8ULL));
        uint_t nibB = (uint_t)((balB & 1ULL) | ((balB>>15) & 2ULL) | ((balB>>30) & 4ULL) | ((balB>>45) & 8ULL));
        uint_t oct = nibA | (nibB << 4);          // 8 bits at j0 (8-aligned)
        int w = j0 >> 5;
        if (w != curW){
            if (wacc && lane == 0) atomicOr(&mbits[curW], wacc);
            wacc = 0; curW = w;
        }
        wacc |= oct << (j0 & 31);
        msum += (float)__popc(oct);
    }
    if (wacc && lane == 0) atomicOr(&mbits[curW], wacc);
    if (lane == 0) dinv[wave] = rsqrtf(msum + 1.0f);
}

// ================= item-side masked degree =================
__global__ __launch_bounds__(256) void k_itemdeg(const int* __restrict__ ptr, const uint_t* __restrict__ csr_ip,
                                                 const uint_t* __restrict__ mbits, float* __restrict__ dinv){
    int wave = (blockIdx.x*blockDim.x + threadIdx.x) >> 6;
    if (wave >= NIs) return;
    int n = NUs + wave;
    int lane = threadIdx.x & 63;
    int jb = ptr[n], je = ptr[n+1];
    float s = 0.f;
    for (int j = jb + lane; j < je; j += 64){
        uint_t upos = csr_ip[j - NEs];
        s += (float)((mbits[upos >> 5] >> (upos & 31)) & 1u);
    }
    #pragma unroll
    for (int k = 1; k < 64; k <<= 1) s += __shfl_xor(s, k, 64);
    if (lane == 0) dinv[n] = rsqrtf(s + 1.0f);
}

// ================= unmasked dinv =================
__global__ void k_dinvcnt(const int* __restrict__ ptr, float* __restrict__ dinv){
    int n = blockIdx.x*blockDim.x + threadIdx.x;
    if (n < NNs) dinv[n] = rsqrtf((float)(ptr[n+1]-ptr[n]) + 1.0f);
}

// ================= MFMA 64x64 GEMM: gB = bf16((ego@W^T)*dinv[row]) =================
__global__ __launch_bounds__(256) void k_gemmM(const float* __restrict__ ego, const float* __restrict__ W,
                                               const float* __restrict__ dinv, ushort_t* __restrict__ gB){
    int tid = threadIdx.x;
    int wv = tid >> 6, lane = tid & 63;
    int rbase = (blockIdx.x*4 + wv) * 16;
    int c16 = lane & 15;
    int ks = (lane >> 4) * 8;
    const float* ar = ego + (size_t)(rbase + c16)*64;
    bf16x8 ah0, al0, ah1, al1;
    #pragma unroll
    for (int j = 0; j < 8; j++){
        float a = ar[ks + j];
        ushort_t h = f2bf(a); ah0[j] = (short)h; al0[j] = (short)f2bf(a - bf2f(h));
        float b = ar[32 + ks + j];
        ushort_t g = f2bf(b); ah1[j] = (short)g; al1[j] = (short)f2bf(b - bf2f(g));
    }
    float dv[4];
    #pragma unroll
    for (int j = 0; j < 4; j++) dv[j] = dinv[rbase + (lane >> 4)*4 + j];
    #pragma unroll
    for (int ct = 0; ct < 4; ct++){
        const float* wr = W + (size_t)(ct*16 + c16)*64;
        bf16x8 wh0, wl0, wh1, wl1;
        #pragma unroll
        for (int j = 0; j < 8; j++){
            float w = wr[ks + j];
            ushort_t h = f2bf(w); wh0[j] = (short)h; wl0[j] = (short)f2bf(w - bf2f(h));
            float x = wr[32 + ks + j];
            ushort_t g = f2bf(x); wh1[j] = (short)g; wl1[j] = (short)f2bf(x - bf2f(g));
        }
        f32x4 acc = {0.f, 0.f, 0.f, 0.f};
        acc = __builtin_amdgcn_mfma_f32_16x16x32_bf16(ah0, wh0, acc, 0, 0, 0);
        acc = __builtin_amdgcn_mfma_f32_16x16x32_bf16(al0, wh0, acc, 0, 0, 0);
        acc = __builtin_amdgcn_mfma_f32_16x16x32_bf16(ah0, wl0, acc, 0, 0, 0);
        acc = __builtin_amdgcn_mfma_f32_16x16x32_bf16(ah1, wh1, acc, 0, 0, 0);
        acc = __builtin_amdgcn_mfma_f32_16x16x32_bf16(al1, wh1, acc, 0, 0, 0);
        acc = __builtin_amdgcn_mfma_f32_16x16x32_bf16(ah1, wl1, acc, 0, 0, 0);
        #pragma unroll
        for (int j = 0; j < 4; j++){
            int row = rbase + (lane >> 4)*4 + j;
            gB[(size_t)row*64 + ct*16 + c16] = f2bf(acc[j] * dv[j]);
        }
    }
}

// ================= combined aggregation (R12 proven form) =================
template<bool MASKED>
__global__ __launch_bounds__(256) void k_agg(const int* __restrict__ ptr, const ushort_t* __restrict__ csr_u,
                                             const ushort_t* __restrict__ csr_iu,
                                             const uint_t* __restrict__ csr_ip,
                                             const uint_t* __restrict__ mbits,
                                             const ushort_t* __restrict__ gB, const float* __restrict__ dinv,
                                             const float* __restrict__ bias,
                                             float* __restrict__ egon, float* __restrict__ accm){
    int wave = (blockIdx.x*blockDim.x + threadIdx.x) >> 6;
    if (wave >= NNs) return;
    int lane = threadIdx.x & 63;
    int q = lane >> 3, r = lane & 7;     // 8 groups x 8 lanes; each lane covers 8 bf16 cols (16B)
    int jb = ptr[wave], je = ptr[wave+1];
    float acc[8] = {};

    #define ADDROW(row) { \
        uint4 w_ = *reinterpret_cast<const uint4*>(gB + (size_t)(row)*64 + r*8); \
        acc[0] += __uint_as_float(w_.x << 16); acc[1] += __uint_as_float(w_.x & 0xFFFF0000u); \
        acc[2] += __uint_as_float(w_.y << 16); acc[3] += __uint_as_float(w_.y & 0xFFFF0000u); \
        acc[4] += __uint_as_float(w_.z << 16); acc[5] += __uint_as_float(w_.z & 0xFFFF0000u); \
        acc[6] += __uint_as_float(w_.w << 16); acc[7] += __uint_as_float(w_.w & 0xFFFF0000u); }

    if (wave < NUs){
        int j = jb + q;
        for (; j + 8 < je; j += 16){
            int i0 = csr_u[j], i1 = csr_u[j+8];
            bool w0 = true, w1 = true;
            if (MASKED){
                w0 = (mbits[j>>5] >> (j&31)) & 1u;
                w1 = (mbits[(j+8)>>5] >> ((j+8)&31)) & 1u;
            }
            if (w0) ADDROW(NUs + i0);
            if (w1) ADDROW(NUs + i1);
        }
        if (j < je){
            bool w0 = true;
            if (MASKED) w0 = (mbits[j>>5] >> (j&31)) & 1u;
            if (w0) ADDROW(NUs + (int)csr_u[j]);
        }
    } else {
        const ushort_t* ciu = csr_iu - NEs;
        const uint_t*   cip = csr_ip - NEs;
        int j = jb + q;
        for (; j + 8 < je; j += 16){
            int u0 = ciu[j], u1 = ciu[j+8];
            bool w0 = true, w1 = true;
            if (MASKED){
                uint_t a0 = cip[j], a1 = cip[j+8];
                w0 = (mbits[a0>>5] >> (a0&31)) & 1u;
                w1 = (mbits[a1>>5] >> (a1&31)) & 1u;
            }
            if (w0) ADDROW(u0);
            if (w1) ADDROW(u1);
        }
        if (j < je){
            int u0 = ciu[j];
            bool w0 = true;
            if (MASKED){
                uint_t a0 = cip[j];
                w0 = (mbits[a0>>5] >> (a0&31)) & 1u;
            }
            if (w0) ADDROW(u0);
        }
    }
    #undef ADDROW

    #pragma unroll
    for (int k = 0; k < 8; k++){
        acc[k] += __shfl_xor(acc[k], 8, 64);
        acc[k] += __shfl_xor(acc[k], 16, 64);
        acc[k] += __shfl_xor(acc[k], 32, 64);
    }
    if (q == 0){
        float dn = dinv[wave];
        uint4 w_ = *reinterpret_cast<const uint4*>(gB + (size_t)wave*64 + r*8);
        float gs[8];
        gs[0] = __uint_as_float(w_.x << 16); gs[1] = __uint_as_float(w_.x & 0xFFFF0000u);
        gs[2] = __uint_as_float(w_.y << 16); gs[3] = __uint_as_float(w_.y & 0xFFFF0000u);
        gs[4] = __uint_as_float(w_.z << 16); gs[5] = __uint_as_float(w_.z & 0xFFFF0000u);
        gs[6] = __uint_as_float(w_.w << 16); gs[7] = __uint_as_float(w_.w & 0xFFFF0000u);
        float o[8];
        #pragma unroll
        for (int k = 0; k < 8; k++) o[k] = dn*(acc[k] + gs[k]) + bias[r*8 + k];
        float* eg = egon + (size_t)wave*64 + r*8;
        float* am = accm + (size_t)wave*64 + r*8;
        float4 o0 = {o[0],o[1],o[2],o[3]}, o1 = {o[4],o[5],o[6],o[7]};
        st4(eg, o0); st4(eg+4, o1);
        float4 a0 = ld4(am), a1 = ld4(am+4);
        a0.x+=o[0]; a0.y+=o[1]; a0.z+=o[2]; a0.w+=o[3];
        a1.x+=o[4]; a1.y+=o[5]; a1.z+=o[6]; a1.w+=o[7];
        st4(am, a0); st4(am+4, a1);
    }
}

// ================= final =================
__global__ __launch_bounds__(256) void k_final(const float* __restrict__ accm, const float* __restrict__ extra,
                                               float* __restrict__ out, int p){
    int i = blockIdx.x*blockDim.x + threadIdx.x;
    if (i >= NNs*16) return;
    int n = i >> 4, c = i & 15;
    float4 v = ld4(accm + (size_t)n*64 + c*4);
    const float third = 1.0f/3.0f;
    v.x *= third; v.y *= third; v.z *= third; v.w *= third;
    if (n >= NUs){
        float4 e = ld4(extra + (size_t)(n-NUs)*64 + c*4);
        v.x += e.x; v.y += e.y; v.z += e.z; v.w += e.w;
    }
    st4(out + (size_t)n*192 + p*64 + c*4, v);
}

extern "C" void kernel_launch(void* const* d_in, const int* in_sizes, int n_in,
                              void* d_out, int out_size, void* d_ws, size_t ws_size,
                              hipStream_t stream){
    const float* user_emb = (const float*)d_in[0];
    const float* item_emb = (const float*)d_in[1];
    const float* v_feat   = (const float*)d_in[2];
    const float* t_feat   = (const float*)d_in[3];
    const float* Wi       = (const float*)d_in[4];
    const float* bi       = (const float*)d_in[5];
    const float* Wt       = (const float*)d_in[6];
    const float* bt       = (const float*)d_in[7];
    const float* convW    = (const float*)d_in[8];
    const float* convb    = (const float*)d_in[9];
    const int*   edge     = (const int*)d_in[10];
    const int*   img_idx  = (const int*)d_in[11];
    const float* img_vals = (const float*)d_in[12];
    const int*   txt_idx  = (const int*)d_in[13];
    const float* txt_vals = (const float*)d_in[14];
    const int*   mm_idx   = (const int*)d_in[15];
    const float* mm_vals  = (const float*)d_in[16];
    float* out = (float*)d_out;

    const int* eu = edge;
    const int* ev = edge + NEs;

    char* wsb = (char*)d_ws;
    size_t off = 0;
    auto alloc = [&](size_t b)->char*{ char* p = wsb + off; off = (off + b + 255) & ~(size_t)255; return p; };
    int*      ptr    = (int*)     alloc((size_t)(NNs+1)*4);
    int*      Cflat  = (int*)     alloc((size_t)L1*4);
    int*      bsums  = (int*)     alloc(256*4);
    uint_t*   stageu = (uint_t*)  alloc((size_t)NEs*4);
    ull_t*    itemin = (ull_t*)   alloc((size_t)NEs*8);
    ull_t*    stagei = (ull_t*)   alloc((size_t)NEs*8);
    ushort_t* csr_u  = (ushort_t*)alloc((size_t)NEs*2);
    ushort_t* csr_iu = (ushort_t*)alloc((size_t)NEs*2);
    uint_t*   csr_ip = (uint_t*)  alloc((size_t)NEs*4);
    uint_t*   mbits  = (uint_t*)  alloc((size_t)((NEs+63)/64)*8);
    float*    dinv   = (float*)   alloc((size_t)NNs*4);
    float*    ego_a  = (float*)   alloc((size_t)NNs*64*4);
    float*    ego_b  = (float*)   alloc((size_t)NNs*64*4);
    ushort_t* gB     = (ushort_t*)alloc((size_t)NNs*64*2);
    float*    accm   = (float*)   alloc((size_t)NNs*64*4);
    float*    vemb   = (float*)   alloc((size_t)NIs*64*4);
    float*    temb   = (float*)   alloc((size_t)NIs*64*4);
    float*    hbuf   = (float*)   alloc((size_t)NIs*64*4);
    float*    h1buf  = (float*)   alloc((size_t)NIs*64*4);
    float*    h2buf  = (float*)   alloc((size_t)NIs*64*4);

    // ---- CSR build: user bucket sort ----
    k_u1cnt<<<NB1, 256, 0, stream>>>(eu, Cflat);
    k_scanA<<<NSA, 256, 0, stream>>>((const int4*)Cflat, Cflat, bsums);
    k_scanB<<<1, 256, 0, stream>>>(bsums);
    k_scanC<<<NSA, 256, 0, stream>>>((int4*)Cflat, bsums);
    k_u1scat<<<NB1, 256, 0, stream>>>(eu, ev, Cflat, stageu);
    k_u2<<<256, 256, 0, stream>>>(stageu, Cflat, ptr, csr_u, itemin);
    // ---- CSR build: item bucket sort (carries upos) ----
    k_i1cnt<<<NB1, 256, 0, stream>>>(itemin, Cflat);
    k_scanA<<<NSA, 256, 0, stream>>>((const int4*)Cflat, Cflat, bsums);
    k_scanB<<<1, 256, 0, stream>>>(bsums);
    k_scanC<<<NSA, 256, 0, stream>>>((int4*)Cflat, bsums);
    k_i1scat<<<NB1, 256, 0, stream>>>(itemin, Cflat, stagei);
    k_i2<<<256, 256, 0, stream>>>(stagei, Cflat, ptr, csr_iu, csr_ip);

    // ---- feature embeddings (MFMA) ----
    k_featM<1024><<<128, 256, 0, stream>>>(v_feat, Wi, bi, vemb);
    k_featM<384> <<<128, 256, 0, stream>>>(t_feat, Wt, bt, temb);

    // ---- KNN spmm + l2norm ----
    k_spmm_l2<<<2048, 256, 0, stream>>>(mm_idx,  mm_vals,  item_emb, hbuf,  163840, 2);
    k_spmm_l2<<<2048, 256, 0, stream>>>(img_idx, img_vals, vemb,     h1buf, 81920, 1);
    k_spmm_l2<<<2048, 256, 0, stream>>>(txt_idx, txt_vals, temb,     h2buf, 81920, 1);

    // ---- propagates ----
    auto propagate = [&](const float* item_part, bool filtered, const float* extra, int pcol){
        k_init<<<2560, 256, 0, stream>>>(user_emb, item_part, ego_a, accm);
        float* cur = ego_a; float* nxt = ego_b;
        if (!filtered) k_dinvcnt<<<160, 256, 0, stream>>>(ptr, dinv);
        for (int l = 0; l < 2; l++){
            if (filtered){
                hipMemsetAsync(mbits, 0, (size_t)((NEs+63)/64)*8, stream);
                k_mask<<<8192, 256, 0, stream>>>(ptr, csr_u, cur, mbits, dinv);
                k_itemdeg<<<2048, 256, 0, stream>>>(ptr, csr_ip, mbits, dinv);
            }
            k_gemmM<<<640, 256, 0, stream>>>(cur, convW + l*64*64, dinv, gB);
            if (filtered)
                k_agg<true><<<10240, 256, 0, stream>>>(ptr, csr_u, csr_iu, csr_ip, mbits, gB, dinv, convb + l*64, nxt, accm);
            else
                k_agg<false><<<10240, 256, 0, stream>>>(ptr, csr_u, csr_iu, nullptr, nullptr, gB, dinv, convb + l*64, nxt, accm);
            float* t = cur; cur = nxt; nxt = t;
        }
        k_final<<<2560, 256, 0, stream>>>(accm, extra, out, pcol);
    };

    propagate(vemb,     true,  h1buf, 1);   // u_v / i_v
    propagate(temb,     true,  h2buf, 2);   // u_t / i_t
    propagate(item_emb, false, hbuf,  0);   // u_g / i_g
}

// Round 15
// 853.319 us; speedup vs baseline: 1.1280x; 1.0248x over previous
//
#include <hip/hip_runtime.h>
#include <cmath>

#define NUs 32768
#define NIs 8192
#define NNs 40960   // NUs + NIs
#define NEs 2000000
#define CHUNK 2048
#define NB1 977          // ceil(NEs/CHUNK)
#define L1 (256*NB1)     // flat count array length = 250112
#define L4 (L1/4)        // 62528
#define NSA 245          // ceil(L4/256)

typedef unsigned short ushort_t;
typedef unsigned int uint_t;
typedef unsigned long long ull_t;
typedef __attribute__((ext_vector_type(8))) short bf16x8;
typedef __attribute__((ext_vector_type(4))) float f32x4;

__device__ __forceinline__ float4 ld4(const float* p){ return *reinterpret_cast<const float4*>(p); }
__device__ __forceinline__ void st4(float* p, float4 v){ *reinterpret_cast<float4*>(p) = v; }
__device__ __forceinline__ ushort_t f2bf(float f){
    uint_t u = __float_as_uint(f);
    return (ushort_t)((u + 0x7FFFu + ((u >> 16) & 1u)) >> 16);   // RNE
}
__device__ __forceinline__ float bf2f(ushort_t h){ return __uint_as_float((uint_t)h << 16); }

// ================= atomic-free CSR build via two bucket sorts =================

__global__ __launch_bounds__(256) void k_scanA(const int4* __restrict__ in4, int* __restrict__ out,
                                               int* __restrict__ bsums){
    __shared__ int s[256];
    int t = threadIdx.x; int i = blockIdx.x*256 + t;
    int4 v = {0,0,0,0};
    if (i < L4) v = in4[i];
    int sum = v.x+v.y+v.z+v.w;
    s[t] = sum; __syncthreads();
    for (int off=1; off<256; off<<=1){
        int x = (t>=off)? s[t-off] : 0;
        __syncthreads(); s[t] += x; __syncthreads();
    }
    int excl = s[t]-sum;
    if (t == 255) bsums[blockIdx.x] = s[255];
    if (i < L4){
        int o = excl;
        out[4*i]   = o; o += v.x;
        out[4*i+1] = o; o += v.y;
        out[4*i+2] = o; o += v.z;
        out[4*i+3] = o;
    }
}
__global__ void k_scanB(int* __restrict__ b){
    __shared__ int s[256];
    int t = threadIdx.x;
    int v = (t < NSA)? b[t] : 0;
    s[t] = v; __syncthreads();
    for (int off=1; off<256; off<<=1){
        int x = (t>=off)? s[t-off] : 0;
        __syncthreads(); s[t] += x; __syncthreads();
    }
    if (t < NSA) b[t] = s[t]-v;
}
__global__ __launch_bounds__(256) void k_scanC(int4* __restrict__ out, const int* __restrict__ bo){
    int i = blockIdx.x*256 + threadIdx.x;
    if (i >= L4) return;
    int a = bo[blockIdx.x];
    int4 v = out[i]; v.x+=a; v.y+=a; v.z+=a; v.w+=a; out[i] = v;
}

__global__ __launch_bounds__(256) void k_u1cnt(const int* __restrict__ eu, int* __restrict__ C){
    __shared__ int h[256];
    int t = threadIdx.x; h[t] = 0; __syncthreads();
    int base = blockIdx.x*CHUNK;
    #pragma unroll
    for (int k = 0; k < 8; k++){
        int e = base + k*256 + t;
        if (e < NEs) atomicAdd(&h[eu[e]>>7], 1);
    }
    __syncthreads();
    C[t*NB1 + blockIdx.x] = h[t];
}
__global__ __launch_bounds__(256) void k_u1scat(const int* __restrict__ eu, const int* __restrict__ ev,
                                                const int* __restrict__ off, uint_t* __restrict__ stage){
    __shared__ int bo[256]; __shared__ int rk[256];
    int t = threadIdx.x;
    bo[t] = off[t*NB1 + blockIdx.x]; rk[t] = 0;
    __syncthreads();
    int base = blockIdx.x*CHUNK;
    #pragma unroll
    for (int k = 0; k < 8; k++){
        int e = base + k*256 + t;
        if (e < NEs){
            int u = eu[e]; int b = u>>7;
            int r = atomicAdd(&rk[b], 1);
            stage[bo[b]+r] = ((uint_t)u<<13) | (uint_t)(ev[e]-NUs);
        }
    }
}
__global__ __launch_bounds__(256) void k_u2(const uint_t* __restrict__ stage, const int* __restrict__ off,
                                            int* __restrict__ ptr, ushort_t* __restrict__ csr_u,
                                            ull_t* __restrict__ itemin){
    __shared__ int h[128], lb[128], rk[128];
    int b = blockIdx.x, t = threadIdx.x;
    int base = off[b*NB1];
    int end  = (b == 255)? NEs : off[(b+1)*NB1];
    if (t < 128){ h[t] = 0; rk[t] = 0; }
    __syncthreads();
    for (int i = base+t; i < end; i += 256) atomicAdd(&h[(stage[i]>>13)&127], 1);
    __syncthreads();
    if (t < 128) lb[t] = h[t];
    __syncthreads();
    for (int o = 1; o < 128; o <<= 1){
        int x = 0;
        if (t < 128 && t >= o) x = lb[t-o];
        __syncthreads();
        if (t < 128) lb[t] += x;
        __syncthreads();
    }
    if (t < 128){
        int excl = lb[t] - h[t];
        ptr[b*128 + t] = base + excl;
        lb[t] = base + excl;
    }
    __syncthreads();
    for (int i = base+t; i < end; i += 256){
        uint_t p = stage[i];
        int u = (int)(p>>13), item = (int)(p & 0x1FFFu);
        int r = atomicAdd(&rk[u&127], 1);
        int pos = lb[u&127] + r;
        csr_u[pos] = (ushort_t)item;
        itemin[pos] = ((ull_t)item<<36) | ((ull_t)pos<<15) | (ull_t)u;
    }
}
__global__ __launch_bounds__(256) void k_i1cnt(const ull_t* __restrict__ itemin, int* __restrict__ C){
    __shared__ int h[256];
    int t = threadIdx.x; h[t] = 0; __syncthreads();
    int base = blockIdx.x*CHUNK;
    #pragma unroll
    for (int k = 0; k < 8; k++){
        int e = base + k*256 + t;
        if (e < NEs) atomicAdd(&h[(int)((itemin[e]>>41)&255ULL)], 1);
    }
    __syncthreads();
    C[t*NB1 + blockIdx.x] = h[t];
}
__global__ __launch_bounds__(256) void k_i1scat(const ull_t* __restrict__ itemin, const int* __restrict__ off,
                                                ull_t* __restrict__ stage){
    __shared__ int bo[256]; __shared__ int rk[256];
    int t = threadIdx.x;
    bo[t] = off[t*NB1 + blockIdx.x]; rk[t] = 0;
    __syncthreads();
    int base = blockIdx.x*CHUNK;
    #pragma unroll
    for (int k = 0; k < 8; k++){
        int e = base + k*256 + t;
        if (e < NEs){
            ull_t p = itemin[e];
            int b = (int)((p>>41)&255ULL);
            int r = atomicAdd(&rk[b], 1);
            stage[bo[b]+r] = p;
        }
    }
}
__global__ __launch_bounds__(256) void k_i2(const ull_t* __restrict__ stage, const int* __restrict__ off,
                                            int* __restrict__ ptr, ushort_t* __restrict__ csr_iu,
                                            uint_t* __restrict__ csr_ip){
    __shared__ int h[32], lb[32], rk[32];
    int b = blockIdx.x, t = threadIdx.x;
    int base = off[b*NB1];
    int end  = (b == 255)? NEs : off[(b+1)*NB1];
    if (t < 32){ h[t] = 0; rk[t] = 0; }
    __syncthreads();
    for (int i = base+t; i < end; i += 256) atomicAdd(&h[(int)((stage[i]>>36)&31ULL)], 1);
    __syncthreads();
    if (t < 32) lb[t] = h[t];
    __syncthreads();
    for (int o = 1; o < 32; o <<= 1){
        int x = 0;
        if (t < 32 && t >= o) x = lb[t-o];
        __syncthreads();
        if (t < 32) lb[t] += x;
        __syncthreads();
    }
    if (t < 32){
        int excl = lb[t] - h[t];
        ptr[NUs + b*32 + t] = NEs + base + excl;
        lb[t] = base + excl;
    }
    if (b == 255 && t == 0) ptr[NNs] = 2*NEs;
    __syncthreads();
    for (int i = base+t; i < end; i += 256){
        ull_t p = stage[i];
        int key = (int)((p>>36)&31ULL);
        int r = atomicAdd(&rk[key], 1);
        int pos = lb[key] + r;
        csr_iu[pos] = (ushort_t)(p & 32767ULL);
        csr_ip[pos] = (uint_t)((p >> 15) & 0x1FFFFFULL);
    }
}

// ================= MFMA feature GEMM =================
template<int K>
__global__ __launch_bounds__(256) void k_featM(const float* __restrict__ A, const float* __restrict__ W,
                                               const float* __restrict__ bias, float* __restrict__ out){
    int tid = threadIdx.x;
    int wv = tid >> 6, lane = tid & 63;
    int rbase = (blockIdx.x*4 + wv) * 16;
    int c16 = lane & 15;
    int ks8 = (lane >> 4) * 8;
    f32x4 acc0 = {0,0,0,0}, acc1 = {0,0,0,0}, acc2 = {0,0,0,0}, acc3 = {0,0,0,0};
    for (int kt = 0; kt < K; kt += 32){
        const float* ar = A + (size_t)(rbase + c16)*K + kt + ks8;
        bf16x8 ah, al;
        #pragma unroll
        for (int j = 0; j < 8; j++){
            float a = ar[j];
            ushort_t h = f2bf(a); ah[j] = (short)h; al[j] = (short)f2bf(a - bf2f(h));
        }
        #pragma unroll
        for (int ct = 0; ct < 4; ct++){
            const float* wr = W + (size_t)(ct*16 + c16)*K + kt + ks8;
            bf16x8 wh, wl;
            #pragma unroll
            for (int j = 0; j < 8; j++){
                float w = wr[j];
                ushort_t h = f2bf(w); wh[j] = (short)h; wl[j] = (short)f2bf(w - bf2f(h));
            }
            f32x4 acc = (ct==0)? acc0 : (ct==1)? acc1 : (ct==2)? acc2 : acc3;
            acc = __builtin_amdgcn_mfma_f32_16x16x32_bf16(ah, wh, acc, 0, 0, 0);
            acc = __builtin_amdgcn_mfma_f32_16x16x32_bf16(al, wh, acc, 0, 0, 0);
            acc = __builtin_amdgcn_mfma_f32_16x16x32_bf16(ah, wl, acc, 0, 0, 0);
            if (ct==0) acc0 = acc; else if (ct==1) acc1 = acc; else if (ct==2) acc2 = acc; else acc3 = acc;
        }
    }
    #pragma unroll
    for (int ct = 0; ct < 4; ct++){
        f32x4 acc = (ct==0)? acc0 : (ct==1)? acc1 : (ct==2)? acc2 : acc3;
        float bb = bias[ct*16 + c16];
        #pragma unroll
        for (int j = 0; j < 4; j++){
            int row = rbase + (lane >> 4)*4 + j;
            out[(size_t)row*64 + ct*16 + c16] = acc[j] + bb;
        }
    }
}

// ================= KNN SpMM + l2norm =================
__global__ __launch_bounds__(256) void k_spmm_l2(const int* __restrict__ idx, const float* __restrict__ vals,
                                                 const float* __restrict__ src, float* __restrict__ out,
                                                 int stride, int parts){
    int wave = (blockIdx.x*blockDim.x + threadIdx.x) >> 6;
    if (wave >= NIs) return;
    int lane = threadIdx.x & 63;
    const int* cols = idx + stride;
    float acc = 0.f;
    for (int part = 0; part < parts; part++){
        int base = part*81920 + wave*10;
        #pragma unroll
        for (int j = 0; j < 10; j++){
            int e = base + j;
            acc += vals[e] * src[(size_t)cols[e]*64 + lane];
        }
    }
    float ss = acc*acc;
    #pragma unroll
    for (int mset = 1; mset < 64; mset <<= 1) ss += __shfl_xor(ss, mset, 64);
    float nrm = fmaxf(sqrtf(ss), 1e-12f);
    out[(size_t)wave*64 + lane] = acc / nrm;
}

// ================= propagate init =================
__global__ __launch_bounds__(256) void k_init(const float* __restrict__ ue, const float* __restrict__ it,
                                              float* __restrict__ ego, float* __restrict__ accm){
    int i = blockIdx.x*blockDim.x + threadIdx.x;
    if (i >= NNs*16) return;
    int n = i >> 4, c = i & 15;
    float4 v = (n < NUs) ? ld4(ue + (size_t)n*64 + c*4)
                         : ld4(it + (size_t)(n-NUs)*64 + c*4);
    st4(ego  + (size_t)n*64 + c*4, v);
    st4(accm + (size_t)n*64 + c*4, v);
}

// ================= mask pass: word-aggregated, 2-way unrolled (8 edges/iter) =================
__global__ __launch_bounds__(256) void k_mask(const int* __restrict__ ptr, const ushort_t* __restrict__ csr_u,
                                              const float* __restrict__ ego,
                                              uint_t* __restrict__ mbits, float* __restrict__ dinv){
    int wave = (blockIdx.x*blockDim.x + threadIdx.x) >> 6;
    if (wave >= NUs) return;
    int lane = threadIdx.x & 63;
    int q = lane >> 4, r = lane & 15;
    float4 eu4 = ld4(ego + (size_t)wave*64 + r*4);
    int jb = ptr[wave], je = ptr[wave+1];
    float msum = 0.f; uint_t wacc = 0; int curW = jb >> 5;
    for (int j0 = jb & ~7; j0 < je; j0 += 8){
        int jA = j0 + q, jB = j0 + 4 + q;
        bool vA = (jA >= jb) && (jA < je);
        bool vB = (jB >= jb) && (jB < je);
        int iA = vA ? (int)csr_u[jA] : 0;
        int iB = vB ? (int)csr_u[jB] : 0;
        float4 a = ld4(ego + (size_t)(NUs+iA)*64 + r*4);
        float4 b = ld4(ego + (size_t)(NUs+iB)*64 + r*4);
        float d0 = eu4.x*a.x + eu4.y*a.y + eu4.z*a.z + eu4.w*a.w;
        float d1 = eu4.x*b.x + eu4.y*b.y + eu4.z*b.z + eu4.w*b.w;
        d0 += __shfl_xor(d0, 1, 64); d1 += __shfl_xor(d1, 1, 64);
        d0 += __shfl_xor(d0, 2, 64); d1 += __shfl_xor(d1, 2, 64);
        d0 += __shfl_xor(d0, 4, 64); d1 += __shfl_xor(d1, 4, 64);
        d0 += __shfl_xor(d0, 8, 64); d1 += __shfl_xor(d1, 8, 64);
        ull_t balA = __ballot(vA && (d0 >= 0.f));
        ull_t balB = __ballot(vB && (d1 >= 0.f));
        uint_t nibA = (uint_t)((balA & 1ULL) | ((balA>>15) & 2ULL) | ((balA>>30) & 4ULL) | ((balA>>45) & 8ULL));
        uint_t nibB = (uint_t)((balB & 1ULL) | ((balB>>15) & 2ULL) | ((balB>>30) & 4ULL) | ((balB>>45) & 8ULL));
        uint_t oct = nibA | (nibB << 4);          // 8 bits at j0 (8-aligned)
        int w = j0 >> 5;
        if (w != curW){
            if (wacc && lane == 0) atomicOr(&mbits[curW], wacc);
            wacc = 0; curW = w;
        }
        wacc |= oct << (j0 & 31);
        msum += (float)__popc(oct);
    }
    if (wacc && lane == 0) atomicOr(&mbits[curW], wacc);
    if (lane == 0) dinv[wave] = rsqrtf(msum + 1.0f);
}

// ================= item-side masked degree =================
__global__ __launch_bounds__(256) void k_itemdeg(const int* __restrict__ ptr, const uint_t* __restrict__ csr_ip,
                                                 const uint_t* __restrict__ mbits, float* __restrict__ dinv){
    int wave = (blockIdx.x*blockDim.x + threadIdx.x) >> 6;
    if (wave >= NIs) return;
    int n = NUs + wave;
    int lane = threadIdx.x & 63;
    int jb = ptr[n], je = ptr[n+1];
    float s = 0.f;
    for (int j = jb + lane; j < je; j += 64){
        uint_t upos = csr_ip[j - NEs];
        s += (float)((mbits[upos >> 5] >> (upos & 31)) & 1u);
    }
    #pragma unroll
    for (int k = 1; k < 64; k <<= 1) s += __shfl_xor(s, k, 64);
    if (lane == 0) dinv[n] = rsqrtf(s + 1.0f);
}

// ================= unmasked dinv =================
__global__ void k_dinvcnt(const int* __restrict__ ptr, float* __restrict__ dinv){
    int n = blockIdx.x*blockDim.x + threadIdx.x;
    if (n < NNs) dinv[n] = rsqrtf((float)(ptr[n+1]-ptr[n]) + 1.0f);
}

// ================= MFMA 64x64 GEMM: gB = bf16((ego@W^T)*dinv[row]) =================
__global__ __launch_bounds__(256) void k_gemmM(const float* __restrict__ ego, const float* __restrict__ W,
                                               const float* __restrict__ dinv, ushort_t* __restrict__ gB){
    int tid = threadIdx.x;
    int wv = tid >> 6, lane = tid & 63;
    int rbase = (blockIdx.x*4 + wv) * 16;
    int c16 = lane & 15;
    int ks = (lane >> 4) * 8;
    const float* ar = ego + (size_t)(rbase + c16)*64;
    bf16x8 ah0, al0, ah1, al1;
    #pragma unroll
    for (int j = 0; j < 8; j++){
        float a = ar[ks + j];
        ushort_t h = f2bf(a); ah0[j] = (short)h; al0[j] = (short)f2bf(a - bf2f(h));
        float b = ar[32 + ks + j];
        ushort_t g = f2bf(b); ah1[j] = (short)g; al1[j] = (short)f2bf(b - bf2f(g));
    }
    float dv[4];
    #pragma unroll
    for (int j = 0; j < 4; j++) dv[j] = dinv[rbase + (lane >> 4)*4 + j];
    #pragma unroll
    for (int ct = 0; ct < 4; ct++){
        const float* wr = W + (size_t)(ct*16 + c16)*64;
        bf16x8 wh0, wl0, wh1, wl1;
        #pragma unroll
        for (int j = 0; j < 8; j++){
            float w = wr[ks + j];
            ushort_t h = f2bf(w); wh0[j] = (short)h; wl0[j] = (short)f2bf(w - bf2f(h));
            float x = wr[32 + ks + j];
            ushort_t g = f2bf(x); wh1[j] = (short)g; wl1[j] = (short)f2bf(x - bf2f(g));
        }
        f32x4 acc = {0.f, 0.f, 0.f, 0.f};
        acc = __builtin_amdgcn_mfma_f32_16x16x32_bf16(ah0, wh0, acc, 0, 0, 0);
        acc = __builtin_amdgcn_mfma_f32_16x16x32_bf16(al0, wh0, acc, 0, 0, 0);
        acc = __builtin_amdgcn_mfma_f32_16x16x32_bf16(ah0, wl0, acc, 0, 0, 0);
        acc = __builtin_amdgcn_mfma_f32_16x16x32_bf16(ah1, wh1, acc, 0, 0, 0);
        acc = __builtin_amdgcn_mfma_f32_16x16x32_bf16(al1, wh1, acc, 0, 0, 0);
        acc = __builtin_amdgcn_mfma_f32_16x16x32_bf16(ah1, wl1, acc, 0, 0, 0);
        #pragma unroll
        for (int j = 0; j < 4; j++){
            int row = rbase + (lane >> 4)*4 + j;
            gB[(size_t)row*64 + ct*16 + c16] = f2bf(acc[j] * dv[j]);
        }
    }
}

// ================= combined aggregation: 4-way unrolled conditional-skip =================
template<bool MASKED>
__global__ __launch_bounds__(256) void k_agg(const int* __restrict__ ptr, const ushort_t* __restrict__ csr_u,
                                             const ushort_t* __restrict__ csr_iu,
                                             const uint_t* __restrict__ csr_ip,
                                             const uint_t* __restrict__ mbits,
                                             const ushort_t* __restrict__ gB, const float* __restrict__ dinv,
                                             const float* __restrict__ bias,
                                             float* __restrict__ egon, float* __restrict__ accm){
    int wave = (blockIdx.x*blockDim.x + threadIdx.x) >> 6;
    if (wave >= NNs) return;
    int lane = threadIdx.x & 63;
    int q = lane >> 3, r = lane & 7;     // 8 groups x 8 lanes; each lane covers 8 bf16 cols (16B)
    int jb = ptr[wave], je = ptr[wave+1];
    float acc[8] = {};

    #define ADDROW(row) { \
        uint4 w_ = *reinterpret_cast<const uint4*>(gB + (size_t)(row)*64 + r*8); \
        acc[0] += __uint_as_float(w_.x << 16); acc[1] += __uint_as_float(w_.x & 0xFFFF0000u); \
        acc[2] += __uint_as_float(w_.y << 16); acc[3] += __uint_as_float(w_.y & 0xFFFF0000u); \
        acc[4] += __uint_as_float(w_.z << 16); acc[5] += __uint_as_float(w_.z & 0xFFFF0000u); \
        acc[6] += __uint_as_float(w_.w << 16); acc[7] += __uint_as_float(w_.w & 0xFFFF0000u); }

    if (wave < NUs){
        int j = jb + q;
        for (; j + 24 < je; j += 32){
            int i0 = csr_u[j], i1 = csr_u[j+8], i2 = csr_u[j+16], i3 = csr_u[j+24];
            bool w0 = true, w1 = true, w2 = true, w3 = true;
            if (MASKED){
                w0 = (mbits[j>>5]      >> (j&31))      & 1u;
                w1 = (mbits[(j+8)>>5]  >> ((j+8)&31))  & 1u;
                w2 = (mbits[(j+16)>>5] >> ((j+16)&31)) & 1u;
                w3 = (mbits[(j+24)>>5] >> ((j+24)&31)) & 1u;
            }
            if (w0) ADDROW(NUs + i0);
            if (w1) ADDROW(NUs + i1);
            if (w2) ADDROW(NUs + i2);
            if (w3) ADDROW(NUs + i3);
        }
        for (; j < je; j += 8){
            bool w0 = true;
            if (MASKED) w0 = (mbits[j>>5] >> (j&31)) & 1u;
            if (w0) ADDROW(NUs + (int)csr_u[j]);
        }
    } else {
        const ushort_t* ciu = csr_iu - NEs;
        const uint_t*   cip = csr_ip - NEs;
        int j = jb + q;
        for (; j + 24 < je; j += 32){
            int u0 = ciu[j], u1 = ciu[j+8], u2 = ciu[j+16], u3 = ciu[j+24];
            bool w0 = true, w1 = true, w2 = true, w3 = true;
            if (MASKED){
                uint_t a0 = cip[j], a1 = cip[j+8], a2 = cip[j+16], a3 = cip[j+24];
                w0 = (mbits[a0>>5] >> (a0&31)) & 1u;
                w1 = (mbits[a1>>5] >> (a1&31)) & 1u;
                w2 = (mbits[a2>>5] >> (a2&31)) & 1u;
                w3 = (mbits[a3>>5] >> (a3&31)) & 1u;
            }
            if (w0) ADDROW(u0);
            if (w1) ADDROW(u1);
            if (w2) ADDROW(u2);
            if (w3) ADDROW(u3);
        }
        for (; j < je; j += 8){
            bool w0 = true;
            if (MASKED){
                uint_t a0 = cip[j];
                w0 = (mbits[a0>>5] >> (a0&31)) & 1u;
            }
            if (w0) ADDROW((int)ciu[j]);
        }
    }
    #undef ADDROW

    #pragma unroll
    for (int k = 0; k < 8; k++){
        acc[k] += __shfl_xor(acc[k], 8, 64);
        acc[k] += __shfl_xor(acc[k], 16, 64);
        acc[k] += __shfl_xor(acc[k], 32, 64);
    }
    if (q == 0){
        float dn = dinv[wave];
        uint4 w_ = *reinterpret_cast<const uint4*>(gB + (size_t)wave*64 + r*8);
        float gs[8];
        gs[0] = __uint_as_float(w_.x << 16); gs[1] = __uint_as_float(w_.x & 0xFFFF0000u);
        gs[2] = __uint_as_float(w_.y << 16); gs[3] = __uint_as_float(w_.y & 0xFFFF0000u);
        gs[4] = __uint_as_float(w_.z << 16); gs[5] = __uint_as_float(w_.z & 0xFFFF0000u);
        gs[6] = __uint_as_float(w_.w << 16); gs[7] = __uint_as_float(w_.w & 0xFFFF0000u);
        float o[8];
        #pragma unroll
        for (int k = 0; k < 8; k++) o[k] = dn*(acc[k] + gs[k]) + bias[r*8 + k];
        float* eg = egon + (size_t)wave*64 + r*8;
        float* am = accm + (size_t)wave*64 + r*8;
        float4 o0 = {o[0],o[1],o[2],o[3]}, o1 = {o[4],o[5],o[6],o[7]};
        st4(eg, o0); st4(eg+4, o1);
        float4 a0 = ld4(am), a1 = ld4(am+4);
        a0.x+=o[0]; a0.y+=o[1]; a0.z+=o[2]; a0.w+=o[3];
        a1.x+=o[4]; a1.y+=o[5]; a1.z+=o[6]; a1.w+=o[7];
        st4(am, a0); st4(am+4, a1);
    }
}

// ================= final =================
__global__ __launch_bounds__(256) void k_final(const float* __restrict__ accm, const float* __restrict__ extra,
                                               float* __restrict__ out, int p){
    int i = blockIdx.x*blockDim.x + threadIdx.x;
    if (i >= NNs*16) return;
    int n = i >> 4, c = i & 15;
    float4 v = ld4(accm + (size_t)n*64 + c*4);
    const float third = 1.0f/3.0f;
    v.x *= third; v.y *= third; v.z *= third; v.w *= third;
    if (n >= NUs){
        float4 e = ld4(extra + (size_t)(n-NUs)*64 + c*4);
        v.x += e.x; v.y += e.y; v.z += e.z; v.w += e.w;
    }
    st4(out + (size_t)n*192 + p*64 + c*4, v);
}

extern "C" void kernel_launch(void* const* d_in, const int* in_sizes, int n_in,
                              void* d_out, int out_size, void* d_ws, size_t ws_size,
                              hipStream_t stream){
    const float* user_emb = (const float*)d_in[0];
    const float* item_emb = (const float*)d_in[1];
    const float* v_feat   = (const float*)d_in[2];
    const float* t_feat   = (const float*)d_in[3];
    const float* Wi       = (const float*)d_in[4];
    const float* bi       = (const float*)d_in[5];
    const float* Wt       = (const float*)d_in[6];
    const float* bt       = (const float*)d_in[7];
    const float* convW    = (const float*)d_in[8];
    const float* convb    = (const float*)d_in[9];
    const int*   edge     = (const int*)d_in[10];
    const int*   img_idx  = (const int*)d_in[11];
    const float* img_vals = (const float*)d_in[12];
    const int*   txt_idx  = (const int*)d_in[13];
    const float* txt_vals = (const float*)d_in[14];
    const int*   mm_idx   = (const int*)d_in[15];
    const float* mm_vals  = (const float*)d_in[16];
    float* out = (float*)d_out;

    const int* eu = edge;
    const int* ev = edge + NEs;

    char* wsb = (char*)d_ws;
    size_t off = 0;
    auto alloc = [&](size_t b)->char*{ char* p = wsb + off; off = (off + b + 255) & ~(size_t)255; return p; };
    int*      ptr    = (int*)     alloc((size_t)(NNs+1)*4);
    int*      Cflat  = (int*)     alloc((size_t)L1*4);
    int*      bsums  = (int*)     alloc(256*4);
    uint_t*   stageu = (uint_t*)  alloc((size_t)NEs*4);
    ull_t*    itemin = (ull_t*)   alloc((size_t)NEs*8);
    ull_t*    stagei = (ull_t*)   alloc((size_t)NEs*8);
    ushort_t* csr_u  = (ushort_t*)alloc((size_t)NEs*2);
    ushort_t* csr_iu = (ushort_t*)alloc((size_t)NEs*2);
    uint_t*   csr_ip = (uint_t*)  alloc((size_t)NEs*4);
    uint_t*   mbits  = (uint_t*)  alloc((size_t)((NEs+63)/64)*8);
    float*    dinv   = (float*)   alloc((size_t)NNs*4);
    float*    ego_a  = (float*)   alloc((size_t)NNs*64*4);
    float*    ego_b  = (float*)   alloc((size_t)NNs*64*4);
    ushort_t* gB     = (ushort_t*)alloc((size_t)NNs*64*2);
    float*    accm   = (float*)   alloc((size_t)NNs*64*4);
    float*    vemb   = (float*)   alloc((size_t)NIs*64*4);
    float*    temb   = (float*)   alloc((size_t)NIs*64*4);
    float*    hbuf   = (float*)   alloc((size_t)NIs*64*4);
    float*    h1buf  = (float*)   alloc((size_t)NIs*64*4);
    float*    h2buf  = (float*)   alloc((size_t)NIs*64*4);

    // ---- CSR build: user bucket sort ----
    k_u1cnt<<<NB1, 256, 0, stream>>>(eu, Cflat);
    k_scanA<<<NSA, 256, 0, stream>>>((const int4*)Cflat, Cflat, bsums);
    k_scanB<<<1, 256, 0, stream>>>(bsums);
    k_scanC<<<NSA, 256, 0, stream>>>((int4*)Cflat, bsums);
    k_u1scat<<<NB1, 256, 0, stream>>>(eu, ev, Cflat, stageu);
    k_u2<<<256, 256, 0, stream>>>(stageu, Cflat, ptr, csr_u, itemin);
    // ---- CSR build: item bucket sort (carries upos) ----
    k_i1cnt<<<NB1, 256, 0, stream>>>(itemin, Cflat);
    k_scanA<<<NSA, 256, 0, stream>>>((const int4*)Cflat, Cflat, bsums);
    k_scanB<<<1, 256, 0, stream>>>(bsums);
    k_scanC<<<NSA, 256, 0, stream>>>((int4*)Cflat, bsums);
    k_i1scat<<<NB1, 256, 0, stream>>>(itemin, Cflat, stagei);
    k_i2<<<256, 256, 0, stream>>>(stagei, Cflat, ptr, csr_iu, csr_ip);

    // ---- feature embeddings (MFMA) ----
    k_featM<1024><<<128, 256, 0, stream>>>(v_feat, Wi, bi, vemb);
    k_featM<384> <<<128, 256, 0, stream>>>(t_feat, Wt, bt, temb);

    // ---- KNN spmm + l2norm ----
    k_spmm_l2<<<2048, 256, 0, stream>>>(mm_idx,  mm_vals,  item_emb, hbuf,  163840, 2);
    k_spmm_l2<<<2048, 256, 0, stream>>>(img_idx, img_vals, vemb,     h1buf, 81920, 1);
    k_spmm_l2<<<2048, 256, 0, stream>>>(txt_idx, txt_vals, temb,     h2buf, 81920, 1);

    // ---- propagates ----
    auto propagate = [&](const float* item_part, bool filtered, const float* extra, int pcol){
        k_init<<<2560, 256, 0, stream>>>(user_emb, item_part, ego_a, accm);
        float* cur = ego_a; float* nxt = ego_b;
        if (!filtered) k_dinvcnt<<<160, 256, 0, stream>>>(ptr, dinv);
        for (int l = 0; l < 2; l++){
            if (filtered){
                hipMemsetAsync(mbits, 0, (size_t)((NEs+63)/64)*8, stream);
                k_mask<<<8192, 256, 0, stream>>>(ptr, csr_u, cur, mbits, dinv);
                k_itemdeg<<<2048, 256, 0, stream>>>(ptr, csr_ip, mbits, dinv);
            }
            k_gemmM<<<640, 256, 0, stream>>>(cur, convW + l*64*64, dinv, gB);
            if (filtered)
                k_agg<true><<<10240, 256, 0, stream>>>(ptr, csr_u, csr_iu, csr_ip, mbits, gB, dinv, convb + l*64, nxt, accm);
            else
                k_agg<false><<<10240, 256, 0, stream>>>(ptr, csr_u, csr_iu, nullptr, nullptr, gB, dinv, convb + l*64, nxt, accm);
            float* t = cur; cur = nxt; nxt = t;
        }
        k_final<<<2560, 256, 0, stream>>>(accm, extra, out, pcol);
    };

    propagate(vemb,     true,  h1buf, 1);   // u_v / i_v
    propagate(temb,     true,  h2buf, 2);   // u_t / i_t
    propagate(item_emb, false, hbuf,  0);   // u_g / i_g
}

// Round 16
// 845.224 us; speedup vs baseline: 1.1388x; 1.0096x over previous
//
#include <hip/hip_runtime.h>
#include <cmath>

#define NUs 32768
#define NIs 8192
#define NNs 40960   // NUs + NIs
#define NEs 2000000
#define CHUNK 2048
#define NB1 977          // ceil(NEs/CHUNK)
#define L1 (256*NB1)     // flat count array length = 250112
#define L4 (L1/4)        // 62528
#define NSA 245          // ceil(L4/256)

typedef unsigned short ushort_t;
typedef unsigned int uint_t;
typedef unsigned long long ull_t;
typedef __attribute__((ext_vector_type(8))) short bf16x8;
typedef __attribute__((ext_vector_type(4))) float f32x4;

__device__ __forceinline__ float4 ld4(const float* p){ return *reinterpret_cast<const float4*>(p); }
__device__ __forceinline__ void st4(float* p, float4 v){ *reinterpret_cast<float4*>(p) = v; }
__device__ __forceinline__ ushort_t f2bf(float f){
    uint_t u = __float_as_uint(f);
    return (ushort_t)((u + 0x7FFFu + ((u >> 16) & 1u)) >> 16);   // RNE
}
__device__ __forceinline__ float bf2f(ushort_t h){ return __uint_as_float((uint_t)h << 16); }

// ================= atomic-free CSR build via two bucket sorts =================

__global__ __launch_bounds__(256) void k_scanA(const int4* __restrict__ in4, int* __restrict__ out,
                                               int* __restrict__ bsums){
    __shared__ int s[256];
    int t = threadIdx.x; int i = blockIdx.x*256 + t;
    int4 v = {0,0,0,0};
    if (i < L4) v = in4[i];
    int sum = v.x+v.y+v.z+v.w;
    s[t] = sum; __syncthreads();
    for (int off=1; off<256; off<<=1){
        int x = (t>=off)? s[t-off] : 0;
        __syncthreads(); s[t] += x; __syncthreads();
    }
    int excl = s[t]-sum;
    if (t == 255) bsums[blockIdx.x] = s[255];
    if (i < L4){
        int o = excl;
        out[4*i]   = o; o += v.x;
        out[4*i+1] = o; o += v.y;
        out[4*i+2] = o; o += v.z;
        out[4*i+3] = o;
    }
}
__global__ void k_scanB(int* __restrict__ b){
    __shared__ int s[256];
    int t = threadIdx.x;
    int v = (t < NSA)? b[t] : 0;
    s[t] = v; __syncthreads();
    for (int off=1; off<256; off<<=1){
        int x = (t>=off)? s[t-off] : 0;
        __syncthreads(); s[t] += x; __syncthreads();
    }
    if (t < NSA) b[t] = s[t]-v;
}
__global__ __launch_bounds__(256) void k_scanC(int4* __restrict__ out, const int* __restrict__ bo){
    int i = blockIdx.x*256 + threadIdx.x;
    if (i >= L4) return;
    int a = bo[blockIdx.x];
    int4 v = out[i]; v.x+=a; v.y+=a; v.z+=a; v.w+=a; out[i] = v;
}

__global__ __launch_bounds__(256) void k_u1cnt(const int* __restrict__ eu, int* __restrict__ C){
    __shared__ int h[256];
    int t = threadIdx.x; h[t] = 0; __syncthreads();
    int base = blockIdx.x*CHUNK;
    #pragma unroll
    for (int k = 0; k < 8; k++){
        int e = base + k*256 + t;
        if (e < NEs) atomicAdd(&h[eu[e]>>7], 1);
    }
    __syncthreads();
    C[t*NB1 + blockIdx.x] = h[t];
}
__global__ __launch_bounds__(256) void k_u1scat(const int* __restrict__ eu, const int* __restrict__ ev,
                                                const int* __restrict__ off, uint_t* __restrict__ stage){
    __shared__ int bo[256]; __shared__ int rk[256];
    int t = threadIdx.x;
    bo[t] = off[t*NB1 + blockIdx.x]; rk[t] = 0;
    __syncthreads();
    int base = blockIdx.x*CHUNK;
    #pragma unroll
    for (int k = 0; k < 8; k++){
        int e = base + k*256 + t;
        if (e < NEs){
            int u = eu[e]; int b = u>>7;
            int r = atomicAdd(&rk[b], 1);
            stage[bo[b]+r] = ((uint_t)u<<13) | (uint_t)(ev[e]-NUs);
        }
    }
}
__global__ __launch_bounds__(256) void k_u2(const uint_t* __restrict__ stage, const int* __restrict__ off,
                                            int* __restrict__ ptr, ushort_t* __restrict__ csr_u,
                                            ull_t* __restrict__ itemin){
    __shared__ int h[128], lb[128], rk[128];
    int b = blockIdx.x, t = threadIdx.x;
    int base = off[b*NB1];
    int end  = (b == 255)? NEs : off[(b+1)*NB1];
    if (t < 128){ h[t] = 0; rk[t] = 0; }
    __syncthreads();
    for (int i = base+t; i < end; i += 256) atomicAdd(&h[(stage[i]>>13)&127], 1);
    __syncthreads();
    if (t < 128) lb[t] = h[t];
    __syncthreads();
    for (int o = 1; o < 128; o <<= 1){
        int x = 0;
        if (t < 128 && t >= o) x = lb[t-o];
        __syncthreads();
        if (t < 128) lb[t] += x;
        __syncthreads();
    }
    if (t < 128){
        int excl = lb[t] - h[t];
        ptr[b*128 + t] = base + excl;
        lb[t] = base + excl;
    }
    __syncthreads();
    for (int i = base+t; i < end; i += 256){
        uint_t p = stage[i];
        int u = (int)(p>>13), item = (int)(p & 0x1FFFu);
        int r = atomicAdd(&rk[u&127], 1);
        int pos = lb[u&127] + r;
        csr_u[pos] = (ushort_t)item;
        itemin[pos] = ((ull_t)item<<36) | ((ull_t)pos<<15) | (ull_t)u;
    }
}
__global__ __launch_bounds__(256) void k_i1cnt(const ull_t* __restrict__ itemin, int* __restrict__ C){
    __shared__ int h[256];
    int t = threadIdx.x; h[t] = 0; __syncthreads();
    int base = blockIdx.x*CHUNK;
    #pragma unroll
    for (int k = 0; k < 8; k++){
        int e = base + k*256 + t;
        if (e < NEs) atomicAdd(&h[(int)((itemin[e]>>41)&255ULL)], 1);
    }
    __syncthreads();
    C[t*NB1 + blockIdx.x] = h[t];
}
__global__ __launch_bounds__(256) void k_i1scat(const ull_t* __restrict__ itemin, const int* __restrict__ off,
                                                ull_t* __restrict__ stage){
    __shared__ int bo[256]; __shared__ int rk[256];
    int t = threadIdx.x;
    bo[t] = off[t*NB1 + blockIdx.x]; rk[t] = 0;
    __syncthreads();
    int base = blockIdx.x*CHUNK;
    #pragma unroll
    for (int k = 0; k < 8; k++){
        int e = base + k*256 + t;
        if (e < NEs){
            ull_t p = itemin[e];
            int b = (int)((p>>41)&255ULL);
            int r = atomicAdd(&rk[b], 1);
            stage[bo[b]+r] = p;
        }
    }
}
__global__ __launch_bounds__(256) void k_i2(const ull_t* __restrict__ stage, const int* __restrict__ off,
                                            int* __restrict__ ptr, ushort_t* __restrict__ csr_iu,
                                            uint_t* __restrict__ csr_ip){
    __shared__ int h[32], lb[32], rk[32];
    int b = blockIdx.x, t = threadIdx.x;
    int base = off[b*NB1];
    int end  = (b == 255)? NEs : off[(b+1)*NB1];
    if (t < 32){ h[t] = 0; rk[t] = 0; }
    __syncthreads();
    for (int i = base+t; i < end; i += 256) atomicAdd(&h[(int)((stage[i]>>36)&31ULL)], 1);
    __syncthreads();
    if (t < 32) lb[t] = h[t];
    __syncthreads();
    for (int o = 1; o < 32; o <<= 1){
        int x = 0;
        if (t < 32 && t >= o) x = lb[t-o];
        __syncthreads();
        if (t < 32) lb[t] += x;
        __syncthreads();
    }
    if (t < 32){
        int excl = lb[t] - h[t];
        ptr[NUs + b*32 + t] = NEs + base + excl;
        lb[t] = base + excl;
    }
    if (b == 255 && t == 0) ptr[NNs] = 2*NEs;
    __syncthreads();
    for (int i = base+t; i < end; i += 256){
        ull_t p = stage[i];
        int key = (int)((p>>36)&31ULL);
        int r = atomicAdd(&rk[key], 1);
        int pos = lb[key] + r;
        csr_iu[pos] = (ushort_t)(p & 32767ULL);
        csr_ip[pos] = (uint_t)((p >> 15) & 0x1FFFFFULL);
    }
}

// ================= MFMA feature GEMM =================
template<int K>
__global__ __launch_bounds__(256) void k_featM(const float* __restrict__ A, const float* __restrict__ W,
                                               const float* __restrict__ bias, float* __restrict__ out){
    int tid = threadIdx.x;
    int wv = tid >> 6, lane = tid & 63;
    int rbase = (blockIdx.x*4 + wv) * 16;
    int c16 = lane & 15;
    int ks8 = (lane >> 4) * 8;
    f32x4 acc0 = {0,0,0,0}, acc1 = {0,0,0,0}, acc2 = {0,0,0,0}, acc3 = {0,0,0,0};
    for (int kt = 0; kt < K; kt += 32){
        const float* ar = A + (size_t)(rbase + c16)*K + kt + ks8;
        bf16x8 ah, al;
        #pragma unroll
        for (int j = 0; j < 8; j++){
            float a = ar[j];
            ushort_t h = f2bf(a); ah[j] = (short)h; al[j] = (short)f2bf(a - bf2f(h));
        }
        #pragma unroll
        for (int ct = 0; ct < 4; ct++){
            const float* wr = W + (size_t)(ct*16 + c16)*K + kt + ks8;
            bf16x8 wh, wl;
            #pragma unroll
            for (int j = 0; j < 8; j++){
                float w = wr[j];
                ushort_t h = f2bf(w); wh[j] = (short)h; wl[j] = (short)f2bf(w - bf2f(h));
            }
            f32x4 acc = (ct==0)? acc0 : (ct==1)? acc1 : (ct==2)? acc2 : acc3;
            acc = __builtin_amdgcn_mfma_f32_16x16x32_bf16(ah, wh, acc, 0, 0, 0);
            acc = __builtin_amdgcn_mfma_f32_16x16x32_bf16(al, wh, acc, 0, 0, 0);
            acc = __builtin_amdgcn_mfma_f32_16x16x32_bf16(ah, wl, acc, 0, 0, 0);
            if (ct==0) acc0 = acc; else if (ct==1) acc1 = acc; else if (ct==2) acc2 = acc; else acc3 = acc;
        }
    }
    #pragma unroll
    for (int ct = 0; ct < 4; ct++){
        f32x4 acc = (ct==0)? acc0 : (ct==1)? acc1 : (ct==2)? acc2 : acc3;
        float bb = bias[ct*16 + c16];
        #pragma unroll
        for (int j = 0; j < 4; j++){
            int row = rbase + (lane >> 4)*4 + j;
            out[(size_t)row*64 + ct*16 + c16] = acc[j] + bb;
        }
    }
}

// ================= KNN SpMM + l2norm =================
__global__ __launch_bounds__(256) void k_spmm_l2(const int* __restrict__ idx, const float* __restrict__ vals,
                                                 const float* __restrict__ src, float* __restrict__ out,
                                                 int stride, int parts){
    int wave = (blockIdx.x*blockDim.x + threadIdx.x) >> 6;
    if (wave >= NIs) return;
    int lane = threadIdx.x & 63;
    const int* cols = idx + stride;
    float acc = 0.f;
    for (int part = 0; part < parts; part++){
        int base = part*81920 + wave*10;
        #pragma unroll
        for (int j = 0; j < 10; j++){
            int e = base + j;
            acc += vals[e] * src[(size_t)cols[e]*64 + lane];
        }
    }
    float ss = acc*acc;
    #pragma unroll
    for (int mset = 1; mset < 64; mset <<= 1) ss += __shfl_xor(ss, mset, 64);
    float nrm = fmaxf(sqrtf(ss), 1e-12f);
    out[(size_t)wave*64 + lane] = acc / nrm;
}

// ================= propagate init =================
__global__ __launch_bounds__(256) void k_init(const float* __restrict__ ue, const float* __restrict__ it,
                                              float* __restrict__ ego, float* __restrict__ accm){
    int i = blockIdx.x*blockDim.x + threadIdx.x;
    if (i >= NNs*16) return;
    int n = i >> 4, c = i & 15;
    float4 v = (n < NUs) ? ld4(ue + (size_t)n*64 + c*4)
                         : ld4(it + (size_t)(n-NUs)*64 + c*4);
    st4(ego  + (size_t)n*64 + c*4, v);
    st4(accm + (size_t)n*64 + c*4, v);
}

// ================= mask pass: word-aggregated, 4-way unrolled (16 edges/iter) =================
__global__ __launch_bounds__(256) void k_mask(const int* __restrict__ ptr, const ushort_t* __restrict__ csr_u,
                                              const float* __restrict__ ego,
                                              uint_t* __restrict__ mbits, float* __restrict__ dinv){
    int wave = (blockIdx.x*blockDim.x + threadIdx.x) >> 6;
    if (wave >= NUs) return;
    int lane = threadIdx.x & 63;
    int q = lane >> 4, r = lane & 15;
    float4 eu4 = ld4(ego + (size_t)wave*64 + r*4);
    int jb = ptr[wave], je = ptr[wave+1];
    float msum = 0.f; uint_t wacc = 0; int curW = jb >> 5;
    for (int j0 = jb & ~15; j0 < je; j0 += 16){
        int jA = j0 + q, jB = j0 + 4 + q, jC = j0 + 8 + q, jD = j0 + 12 + q;
        bool vA = (jA >= jb) && (jA < je);
        bool vB = (jB >= jb) && (jB < je);
        bool vC = (jC >= jb) && (jC < je);
        bool vD = (jD >= jb) && (jD < je);
        int iA = vA ? (int)csr_u[jA] : 0;
        int iB = vB ? (int)csr_u[jB] : 0;
        int iC = vC ? (int)csr_u[jC] : 0;
        int iD = vD ? (int)csr_u[jD] : 0;
        float4 a = ld4(ego + (size_t)(NUs+iA)*64 + r*4);
        float4 b = ld4(ego + (size_t)(NUs+iB)*64 + r*4);
        float4 c = ld4(ego + (size_t)(NUs+iC)*64 + r*4);
        float4 d = ld4(ego + (size_t)(NUs+iD)*64 + r*4);
        float d0 = eu4.x*a.x + eu4.y*a.y + eu4.z*a.z + eu4.w*a.w;
        float d1 = eu4.x*b.x + eu4.y*b.y + eu4.z*b.z + eu4.w*b.w;
        float d2 = eu4.x*c.x + eu4.y*c.y + eu4.z*c.z + eu4.w*c.w;
        float d3 = eu4.x*d.x + eu4.y*d.y + eu4.z*d.z + eu4.w*d.w;
        d0 += __shfl_xor(d0, 1, 64); d1 += __shfl_xor(d1, 1, 64);
        d2 += __shfl_xor(d2, 1, 64); d3 += __shfl_xor(d3, 1, 64);
        d0 += __shfl_xor(d0, 2, 64); d1 += __shfl_xor(d1, 2, 64);
        d2 += __shfl_xor(d2, 2, 64); d3 += __shfl_xor(d3, 2, 64);
        d0 += __shfl_xor(d0, 4, 64); d1 += __shfl_xor(d1, 4, 64);
        d2 += __shfl_xor(d2, 4, 64); d3 += __shfl_xor(d3, 4, 64);
        d0 += __shfl_xor(d0, 8, 64); d1 += __shfl_xor(d1, 8, 64);
        d2 += __shfl_xor(d2, 8, 64); d3 += __shfl_xor(d3, 8, 64);
        ull_t balA = __ballot(vA && (d0 >= 0.f));
        ull_t balB = __ballot(vB && (d1 >= 0.f));
        ull_t balC = __ballot(vC && (d2 >= 0.f));
        ull_t balD = __ballot(vD && (d3 >= 0.f));
        uint_t nibA = (uint_t)((balA & 1ULL) | ((balA>>15) & 2ULL) | ((balA>>30) & 4ULL) | ((balA>>45) & 8ULL));
        uint_t nibB = (uint_t)((balB & 1ULL) | ((balB>>15) & 2ULL) | ((balB>>30) & 4ULL) | ((balB>>45) & 8ULL));
        uint_t nibC = (uint_t)((balC & 1ULL) | ((balC>>15) & 2ULL) | ((balC>>30) & 4ULL) | ((balC>>45) & 8ULL));
        uint_t nibD = (uint_t)((balD & 1ULL) | ((balD>>15) & 2ULL) | ((balD>>30) & 4ULL) | ((balD>>45) & 8ULL));
        uint_t hex = nibA | (nibB << 4) | (nibC << 8) | (nibD << 12);   // 16 bits at j0 (16-aligned)
        int w = j0 >> 5;
        if (w != curW){
            if (wacc && lane == 0) atomicOr(&mbits[curW], wacc);
            wacc = 0; curW = w;
        }
        wacc |= hex << (j0 & 31);
        msum += (float)__popc(hex);
    }
    if (wacc && lane == 0) atomicOr(&mbits[curW], wacc);
    if (lane == 0) dinv[wave] = rsqrtf(msum + 1.0f);
}

// ================= item-side masked degree =================
__global__ __launch_bounds__(256) void k_itemdeg(const int* __restrict__ ptr, const uint_t* __restrict__ csr_ip,
                                                 const uint_t* __restrict__ mbits, float* __restrict__ dinv){
    int wave = (blockIdx.x*blockDim.x + threadIdx.x) >> 6;
    if (wave >= NIs) return;
    int n = NUs + wave;
    int lane = threadIdx.x & 63;
    int jb = ptr[n], je = ptr[n+1];
    float s = 0.f;
    for (int j = jb + lane; j < je; j += 64){
        uint_t upos = csr_ip[j - NEs];
        s += (float)((mbits[upos >> 5] >> (upos & 31)) & 1u);
    }
    #pragma unroll
    for (int k = 1; k < 64; k <<= 1) s += __shfl_xor(s, k, 64);
    if (lane == 0) dinv[n] = rsqrtf(s + 1.0f);
}

// ================= unmasked dinv =================
__global__ void k_dinvcnt(const int* __restrict__ ptr, float* __restrict__ dinv){
    int n = blockIdx.x*blockDim.x + threadIdx.x;
    if (n < NNs) dinv[n] = rsqrtf((float)(ptr[n+1]-ptr[n]) + 1.0f);
}

// ================= MFMA 64x64 GEMM: gB = bf16((ego@W^T)*dinv[row]) =================
__global__ __launch_bounds__(256) void k_gemmM(const float* __restrict__ ego, const float* __restrict__ W,
                                               const float* __restrict__ dinv, ushort_t* __restrict__ gB){
    int tid = threadIdx.x;
    int wv = tid >> 6, lane = tid & 63;
    int rbase = (blockIdx.x*4 + wv) * 16;
    int c16 = lane & 15;
    int ks = (lane >> 4) * 8;
    const float* ar = ego + (size_t)(rbase + c16)*64;
    bf16x8 ah0, al0, ah1, al1;
    #pragma unroll
    for (int j = 0; j < 8; j++){
        float a = ar[ks + j];
        ushort_t h = f2bf(a); ah0[j] = (short)h; al0[j] = (short)f2bf(a - bf2f(h));
        float b = ar[32 + ks + j];
        ushort_t g = f2bf(b); ah1[j] = (short)g; al1[j] = (short)f2bf(b - bf2f(g));
    }
    float dv[4];
    #pragma unroll
    for (int j = 0; j < 4; j++) dv[j] = dinv[rbase + (lane >> 4)*4 + j];
    #pragma unroll
    for (int ct = 0; ct < 4; ct++){
        const float* wr = W + (size_t)(ct*16 + c16)*64;
        bf16x8 wh0, wl0, wh1, wl1;
        #pragma unroll
        for (int j = 0; j < 8; j++){
            float w = wr[ks + j];
            ushort_t h = f2bf(w); wh0[j] = (short)h; wl0[j] = (short)f2bf(w - bf2f(h));
            float x = wr[32 + ks + j];
            ushort_t g = f2bf(x); wh1[j] = (short)g; wl1[j] = (short)f2bf(x - bf2f(g));
        }
        f32x4 acc = {0.f, 0.f, 0.f, 0.f};
        acc = __builtin_amdgcn_mfma_f32_16x16x32_bf16(ah0, wh0, acc, 0, 0, 0);
        acc = __builtin_amdgcn_mfma_f32_16x16x32_bf16(al0, wh0, acc, 0, 0, 0);
        acc = __builtin_amdgcn_mfma_f32_16x16x32_bf16(ah0, wl0, acc, 0, 0, 0);
        acc = __builtin_amdgcn_mfma_f32_16x16x32_bf16(ah1, wh1, acc, 0, 0, 0);
        acc = __builtin_amdgcn_mfma_f32_16x16x32_bf16(al1, wh1, acc, 0, 0, 0);
        acc = __builtin_amdgcn_mfma_f32_16x16x32_bf16(ah1, wl1, acc, 0, 0, 0);
        #pragma unroll
        for (int j = 0; j < 4; j++){
            int row = rbase + (lane >> 4)*4 + j;
            gB[(size_t)row*64 + ct*16 + c16] = f2bf(acc[j] * dv[j]);
        }
    }
}

// ================= combined aggregation: 4-way unrolled conditional-skip =================
template<bool MASKED>
__global__ __launch_bounds__(256) void k_agg(const int* __restrict__ ptr, const ushort_t* __restrict__ csr_u,
                                             const ushort_t* __restrict__ csr_iu,
                                             const uint_t* __restrict__ csr_ip,
                                             const uint_t* __restrict__ mbits,
                                             const ushort_t* __restrict__ gB, const float* __restrict__ dinv,
                                             const float* __restrict__ bias,
                                             float* __restrict__ egon, float* __restrict__ accm){
    int wave = (blockIdx.x*blockDim.x + threadIdx.x) >> 6;
    if (wave >= NNs) return;
    int lane = threadIdx.x & 63;
    int q = lane >> 3, r = lane & 7;     // 8 groups x 8 lanes; each lane covers 8 bf16 cols (16B)
    int jb = ptr[wave], je = ptr[wave+1];
    float acc[8] = {};

    #define ADDROW(row) { \
        uint4 w_ = *reinterpret_cast<const uint4*>(gB + (size_t)(row)*64 + r*8); \
        acc[0] += __uint_as_float(w_.x << 16); acc[1] += __uint_as_float(w_.x & 0xFFFF0000u); \
        acc[2] += __uint_as_float(w_.y << 16); acc[3] += __uint_as_float(w_.y & 0xFFFF0000u); \
        acc[4] += __uint_as_float(w_.z << 16); acc[5] += __uint_as_float(w_.z & 0xFFFF0000u); \
        acc[6] += __uint_as_float(w_.w << 16); acc[7] += __uint_as_float(w_.w & 0xFFFF0000u); }

    if (wave < NUs){
        int j = jb + q;
        for (; j + 24 < je; j += 32){
            int i0 = csr_u[j], i1 = csr_u[j+8], i2 = csr_u[j+16], i3 = csr_u[j+24];
            bool w0 = true, w1 = true, w2 = true, w3 = true;
            if (MASKED){
                w0 = (mbits[j>>5]      >> (j&31))      & 1u;
                w1 = (mbits[(j+8)>>5]  >> ((j+8)&31))  & 1u;
                w2 = (mbits[(j+16)>>5] >> ((j+16)&31)) & 1u;
                w3 = (mbits[(j+24)>>5] >> ((j+24)&31)) & 1u;
            }
            if (w0) ADDROW(NUs + i0);
            if (w1) ADDROW(NUs + i1);
            if (w2) ADDROW(NUs + i2);
            if (w3) ADDROW(NUs + i3);
        }
        for (; j < je; j += 8){
            bool w0 = true;
            if (MASKED) w0 = (mbits[j>>5] >> (j&31)) & 1u;
            if (w0) ADDROW(NUs + (int)csr_u[j]);
        }
    } else {
        const ushort_t* ciu = csr_iu - NEs;
        const uint_t*   cip = csr_ip - NEs;
        int j = jb + q;
        for (; j + 24 < je; j += 32){
            int u0 = ciu[j], u1 = ciu[j+8], u2 = ciu[j+16], u3 = ciu[j+24];
            bool w0 = true, w1 = true, w2 = true, w3 = true;
            if (MASKED){
                uint_t a0 = cip[j], a1 = cip[j+8], a2 = cip[j+16], a3 = cip[j+24];
                w0 = (mbits[a0>>5] >> (a0&31)) & 1u;
                w1 = (mbits[a1>>5] >> (a1&31)) & 1u;
                w2 = (mbits[a2>>5] >> (a2&31)) & 1u;
                w3 = (mbits[a3>>5] >> (a3&31)) & 1u;
            }
            if (w0) ADDROW(u0);
            if (w1) ADDROW(u1);
            if (w2) ADDROW(u2);
            if (w3) ADDROW(u3);
        }
        for (; j < je; j += 8){
            bool w0 = true;
            if (MASKED){
                uint_t a0 = cip[j];
                w0 = (mbits[a0>>5] >> (a0&31)) & 1u;
            }
            if (w0) ADDROW((int)ciu[j]);
        }
    }
    #undef ADDROW

    #pragma unroll
    for (int k = 0; k < 8; k++){
        acc[k] += __shfl_xor(acc[k], 8, 64);
        acc[k] += __shfl_xor(acc[k], 16, 64);
        acc[k] += __shfl_xor(acc[k], 32, 64);
    }
    if (q == 0){
        float dn = dinv[wave];
        uint4 w_ = *reinterpret_cast<const uint4*>(gB + (size_t)wave*64 + r*8);
        float gs[8];
        gs[0] = __uint_as_float(w_.x << 16); gs[1] = __uint_as_float(w_.x & 0xFFFF0000u);
        gs[2] = __uint_as_float(w_.y << 16); gs[3] = __uint_as_float(w_.y & 0xFFFF0000u);
        gs[4] = __uint_as_float(w_.z << 16); gs[5] = __uint_as_float(w_.z & 0xFFFF0000u);
        gs[6] = __uint_as_float(w_.w << 16); gs[7] = __uint_as_float(w_.w & 0xFFFF0000u);
        float o[8];
        #pragma unroll
        for (int k = 0; k < 8; k++) o[k] = dn*(acc[k] + gs[k]) + bias[r*8 + k];
        float* eg = egon + (size_t)wave*64 + r*8;
        float* am = accm + (size_t)wave*64 + r*8;
        float4 o0 = {o[0],o[1],o[2],o[3]}, o1 = {o[4],o[5],o[6],o[7]};
        st4(eg, o0); st4(eg+4, o1);
        float4 a0 = ld4(am), a1 = ld4(am+4);
        a0.x+=o[0]; a0.y+=o[1]; a0.z+=o[2]; a0.w+=o[3];
        a1.x+=o[4]; a1.y+=o[5]; a1.z+=o[6]; a1.w+=o[7];
        st4(am, a0); st4(am+4, a1);
    }
}

// ================= final =================
__global__ __launch_bounds__(256) void k_final(const float* __restrict__ accm, const float* __restrict__ extra,
                                               float* __restrict__ out, int p){
    int i = blockIdx.x*blockDim.x + threadIdx.x;
    if (i >= NNs*16) return;
    int n = i >> 4, c = i & 15;
    float4 v = ld4(accm + (size_t)n*64 + c*4);
    const float third = 1.0f/3.0f;
    v.x *= third; v.y *= third; v.z *= third; v.w *= third;
    if (n >= NUs){
        float4 e = ld4(extra + (size_t)(n-NUs)*64 + c*4);
        v.x += e.x; v.y += e.y; v.z += e.z; v.w += e.w;
    }
    st4(out + (size_t)n*192 + p*64 + c*4, v);
}

extern "C" void kernel_launch(void* const* d_in, const int* in_sizes, int n_in,
                              void* d_out, int out_size, void* d_ws, size_t ws_size,
                              hipStream_t stream){
    const float* user_emb = (const float*)d_in[0];
    const float* item_emb = (const float*)d_in[1];
    const float* v_feat   = (const float*)d_in[2];
    const float* t_feat   = (const float*)d_in[3];
    const float* Wi       = (const float*)d_in[4];
    const float* bi       = (const float*)d_in[5];
    const float* Wt       = (const float*)d_in[6];
    const float* bt       = (const float*)d_in[7];
    const float* convW    = (const float*)d_in[8];
    const float* convb    = (const float*)d_in[9];
    const int*   edge     = (const int*)d_in[10];
    const int*   img_idx  = (const int*)d_in[11];
    const float* img_vals = (const float*)d_in[12];
    const int*   txt_idx  = (const int*)d_in[13];
    const float* txt_vals = (const float*)d_in[14];
    const int*   mm_idx   = (const int*)d_in[15];
    const float* mm_vals  = (const float*)d_in[16];
    float* out = (float*)d_out;

    const int* eu = edge;
    const int* ev = edge + NEs;

    char* wsb = (char*)d_ws;
    size_t off = 0;
    auto alloc = [&](size_t b)->char*{ char* p = wsb + off; off = (off + b + 255) & ~(size_t)255; return p; };
    int*      ptr    = (int*)     alloc((size_t)(NNs+1)*4);
    int*      Cflat  = (int*)     alloc((size_t)L1*4);
    int*      bsums  = (int*)     alloc(256*4);
    uint_t*   stageu = (uint_t*)  alloc((size_t)NEs*4);
    ull_t*    itemin = (ull_t*)   alloc((size_t)NEs*8);
    ull_t*    stagei = (ull_t*)   alloc((size_t)NEs*8);
    ushort_t* csr_u  = (ushort_t*)alloc((size_t)NEs*2);
    ushort_t* csr_iu = (ushort_t*)alloc((size_t)NEs*2);
    uint_t*   csr_ip = (uint_t*)  alloc((size_t)NEs*4);
    uint_t*   mbits  = (uint_t*)  alloc((size_t)((NEs+63)/64)*8);
    float*    dinv   = (float*)   alloc((size_t)NNs*4);
    float*    ego_a  = (float*)   alloc((size_t)NNs*64*4);
    float*    ego_b  = (float*)   alloc((size_t)NNs*64*4);
    ushort_t* gB     = (ushort_t*)alloc((size_t)NNs*64*2);
    float*    accm   = (float*)   alloc((size_t)NNs*64*4);
    float*    vemb   = (float*)   alloc((size_t)NIs*64*4);
    float*    temb   = (float*)   alloc((size_t)NIs*64*4);
    float*    hbuf   = (float*)   alloc((size_t)NIs*64*4);
    float*    h1buf  = (float*)   alloc((size_t)NIs*64*4);
    float*    h2buf  = (float*)   alloc((size_t)NIs*64*4);

    // ---- CSR build: user bucket sort ----
    k_u1cnt<<<NB1, 256, 0, stream>>>(eu, Cflat);
    k_scanA<<<NSA, 256, 0, stream>>>((const int4*)Cflat, Cflat, bsums);
    k_scanB<<<1, 256, 0, stream>>>(bsums);
    k_scanC<<<NSA, 256, 0, stream>>>((int4*)Cflat, bsums);
    k_u1scat<<<NB1, 256, 0, stream>>>(eu, ev, Cflat, stageu);
    k_u2<<<256, 256, 0, stream>>>(stageu, Cflat, ptr, csr_u, itemin);
    // ---- CSR build: item bucket sort (carries upos) ----
    k_i1cnt<<<NB1, 256, 0, stream>>>(itemin, Cflat);
    k_scanA<<<NSA, 256, 0, stream>>>((const int4*)Cflat, Cflat, bsums);
    k_scanB<<<1, 256, 0, stream>>>(bsums);
    k_scanC<<<NSA, 256, 0, stream>>>((int4*)Cflat, bsums);
    k_i1scat<<<NB1, 256, 0, stream>>>(itemin, Cflat, stagei);
    k_i2<<<256, 256, 0, stream>>>(stagei, Cflat, ptr, csr_iu, csr_ip);

    // ---- feature embeddings (MFMA) ----
    k_featM<1024><<<128, 256, 0, stream>>>(v_feat, Wi, bi, vemb);
    k_featM<384> <<<128, 256, 0, stream>>>(t_feat, Wt, bt, temb);

    // ---- KNN spmm + l2norm ----
    k_spmm_l2<<<2048, 256, 0, stream>>>(mm_idx,  mm_vals,  item_emb, hbuf,  163840, 2);
    k_spmm_l2<<<2048, 256, 0, stream>>>(img_idx, img_vals, vemb,     h1buf, 81920, 1);
    k_spmm_l2<<<2048, 256, 0, stream>>>(txt_idx, txt_vals, temb,     h2buf, 81920, 1);

    // ---- propagates ----
    auto propagate = [&](const float* item_part, bool filtered, const float* extra, int pcol){
        k_init<<<2560, 256, 0, stream>>>(user_emb, item_part, ego_a, accm);
        float* cur = ego_a; float* nxt = ego_b;
        if (!filtered) k_dinvcnt<<<160, 256, 0, stream>>>(ptr, dinv);
        for (int l = 0; l < 2; l++){
            if (filtered){
                hipMemsetAsync(mbits, 0, (size_t)((NEs+63)/64)*8, stream);
                k_mask<<<8192, 256, 0, stream>>>(ptr, csr_u, cur, mbits, dinv);
                k_itemdeg<<<2048, 256, 0, stream>>>(ptr, csr_ip, mbits, dinv);
            }
            k_gemmM<<<640, 256, 0, stream>>>(cur, convW + l*64*64, dinv, gB);
            if (filtered)
                k_agg<true><<<10240, 256, 0, stream>>>(ptr, csr_u, csr_iu, csr_ip, mbits, gB, dinv, convb + l*64, nxt, accm);
            else
                k_agg<false><<<10240, 256, 0, stream>>>(ptr, csr_u, csr_iu, nullptr, nullptr, gB, dinv, convb + l*64, nxt, accm);
            float* t = cur; cur = nxt; nxt = t;
        }
        k_final<<<2560, 256, 0, stream>>>(accm, extra, out, pcol);
    };

    propagate(vemb,     true,  h1buf, 1);   // u_v / i_v
    propagate(temb,     true,  h2buf, 2);   // u_t / i_t
    propagate(item_emb, false, hbuf,  0);   // u_g / i_g
}